// Round 12
// baseline (314.964 us; speedup 1.0000x reference)
//
#include <hip/hip_runtime.h>
#include <cstddef>

#define EMBED 512
#define NHEADS 8
#define HD 64
#define SEQ 2048
#define NBH 16      // B * NHEADS
#define MROWS 4096  // B * SEQ

typedef __attribute__((ext_vector_type(8))) short bf16x8;
typedef __attribute__((ext_vector_type(4))) float f32x4;

__device__ __forceinline__ unsigned short f2bf(float x) {
    union { float f; unsigned u; } v; v.f = x;
    unsigned r = v.u + 0x7fffu + ((v.u >> 16) & 1u);
    return (unsigned short)(r >> 16);
}
__device__ __forceinline__ float bf2f(unsigned short u) {
    union { unsigned u; float f; } v; v.u = ((unsigned)u) << 16;
    return v.f;
}

// ---------------------------------------------------------------------------
// K0a: split x (fp32) into x_hi + x_lo (bf16 each).
// ---------------------------------------------------------------------------
__global__ __launch_bounds__(256) void cvt_x(
    const float* __restrict__ x, unsigned short* __restrict__ xh,
    unsigned short* __restrict__ xl)
{
    const int i = blockIdx.x * 256 + threadIdx.x;      // float4 index
    float4 v = ((const float4*)x)[i];
    ushort4 h, lo;
    h.x = f2bf(v.x); lo.x = f2bf(v.x - bf2f(h.x));
    h.y = f2bf(v.y); lo.y = f2bf(v.y - bf2f(h.y));
    h.z = f2bf(v.z); lo.z = f2bf(v.z - bf2f(h.z));
    h.w = f2bf(v.w); lo.w = f2bf(v.w - bf2f(h.w));
    ((ushort4*)xh)[i] = h;
    ((ushort4*)xl)[i] = lo;
}

// ---------------------------------------------------------------------------
// K0b: weight transposes to bf16.  z=0..2: Wq/Wk/Wv -> wt[z][n][k] (hi only).
// z=3: Wo hi -> wto[0];  z=4: Wo lo -> wto[1].
// ---------------------------------------------------------------------------
__global__ __launch_bounds__(256) void cvt_w(
    const float* __restrict__ Wq, const float* __restrict__ Wk,
    const float* __restrict__ Wv, const float* __restrict__ Wo,
    unsigned short* __restrict__ wt, unsigned short* __restrict__ wto)
{
    __shared__ float Ws[64][65];
    const int z = blockIdx.z;
    const float* __restrict__ W = (z == 0) ? Wq : (z == 1) ? Wk : (z == 2) ? Wv : Wo;
    const int k0 = blockIdx.x * 64, n0 = blockIdx.y * 64;
    const int t = threadIdx.x;
#pragma unroll
    for (int l = 0; l < 4; ++l) {
        const int idx = t + 256 * l;
        const int r = idx >> 4, c4 = (idx & 15) * 4;
        float4 w = *(const float4*)(W + (size_t)(k0 + r) * EMBED + n0 + c4);
        Ws[r][c4 + 0] = w.x; Ws[r][c4 + 1] = w.y;
        Ws[r][c4 + 2] = w.z; Ws[r][c4 + 3] = w.w;
    }
    __syncthreads();
    unsigned short* __restrict__ dst =
        (z < 3) ? (wt + (size_t)z * EMBED * EMBED)
                : (wto + (size_t)(z - 3) * EMBED * EMBED);
#pragma unroll
    for (int l = 0; l < 4; ++l) {
        const int idx = t + 256 * l;
        const int rn = idx >> 4, k4 = (idx & 15) * 4;
        ushort4 o;
        if (z == 4) {
            float v0 = Ws[k4 + 0][rn], v1 = Ws[k4 + 1][rn];
            float v2 = Ws[k4 + 2][rn], v3 = Ws[k4 + 3][rn];
            o.x = f2bf(v0 - bf2f(f2bf(v0)));
            o.y = f2bf(v1 - bf2f(f2bf(v1)));
            o.z = f2bf(v2 - bf2f(f2bf(v2)));
            o.w = f2bf(v3 - bf2f(f2bf(v3)));
        } else {
            o.x = f2bf(Ws[k4 + 0][rn]);
            o.y = f2bf(Ws[k4 + 1][rn]);
            o.z = f2bf(Ws[k4 + 2][rn]);
            o.w = f2bf(Ws[k4 + 3][rn]);
        }
        *(ushort4*)(dst + (size_t)(n0 + rn) * EMBED + k0 + k4) = o;
    }
}

// ---------------------------------------------------------------------------
// K1: QKV projection on MFMA.  out = (x_hi + x_lo) @ W_z + b_z, bf16 out.
// v written to vt with per-32 kv permutation (so PV B-frags are 16B).
// ---------------------------------------------------------------------------
__global__ __launch_bounds__(256) void mha_qkv_mfma(
    const unsigned short* __restrict__ xh, const unsigned short* __restrict__ xl,
    const unsigned short* __restrict__ wt,
    const float* __restrict__ bq, const float* __restrict__ bk,
    const float* __restrict__ bv,
    unsigned short* __restrict__ qo, unsigned short* __restrict__ ko,
    unsigned short* __restrict__ vt)
{
    const int m0 = blockIdx.x * 64;
    const int z  = blockIdx.y >> 3;
    const int n0 = (blockIdx.y & 7) * 64;
    const float* __restrict__ bias = (z == 0) ? bq : (z == 1) ? bk : bv;

    const int t = threadIdx.x;
    const int w = t >> 6;
    const int lane = t & 63;
    const int g = lane >> 4;
    const int c = lane & 15;

    const short* ah_row = (const short*)xh + (size_t)(m0 + 16 * w + c) * EMBED + 8 * g;
    const short* al_row = (const short*)xl + (size_t)(m0 + 16 * w + c) * EMBED + 8 * g;
    const short* wz = (const short*)wt + (size_t)z * EMBED * EMBED + 8 * g;

    f32x4 acc[4];
#pragma unroll
    for (int s = 0; s < 4; ++s) acc[s] = (f32x4){0.f, 0.f, 0.f, 0.f};

#pragma unroll 4
    for (int ch = 0; ch < 16; ++ch) {
        const int k0 = ch * 32;
        const bf16x8 ah = *(const bf16x8*)(ah_row + k0);
        const bf16x8 al = *(const bf16x8*)(al_row + k0);
#pragma unroll
        for (int s = 0; s < 4; ++s) {
            const bf16x8 bs = *(const bf16x8*)(wz + (size_t)(n0 + 16 * s + c) * EMBED + k0);
            acc[s] = __builtin_amdgcn_mfma_f32_16x16x32_bf16(ah, bs, acc[s], 0, 0, 0);
            acc[s] = __builtin_amdgcn_mfma_f32_16x16x32_bf16(al, bs, acc[s], 0, 0, 0);
        }
    }

    if (z < 2) {
        unsigned short* __restrict__ out = (z == 0) ? qo : ko;
#pragma unroll
        for (int s = 0; s < 4; ++s) {
            const int n = n0 + 16 * s + c;
            const int h = n >> 6, d = n & 63;
            const float bb = bias[n];
#pragma unroll
            for (int r = 0; r < 4; ++r) {
                const int m  = m0 + 16 * w + 4 * g + r;
                const int b_ = m >> 11, sm = m & 2047;
                out[((size_t)(b_ * NHEADS + h) * SEQ + sm) * HD + d] =
                    f2bf(acc[s][r] + bb);
            }
        }
    } else {
        const int m  = m0 + 16 * w + 4 * g;     // base kv of the 4-row chunk
        const int b_ = m >> 11, sm = m & 2047;
        const int a  = sm >> 5, rem = sm & 31;
        const int pos = 32 * a + 8 * ((rem & 15) >> 2) + ((rem >> 4) << 2);
        const int h  = n0 >> 6;
#pragma unroll
        for (int s = 0; s < 4; ++s) {
            const int d = 16 * s + c;
            const float bb = bias[n0 + d];
            ushort4 o;
            o.x = f2bf(acc[s][0] + bb);
            o.y = f2bf(acc[s][1] + bb);
            o.z = f2bf(acc[s][2] + bb);
            o.w = f2bf(acc[s][3] + bb);
            *(ushort4*)(vt + ((size_t)(b_ * NHEADS + h) * HD + d) * SEQ + pos) = o;
        }
    }
}

// ---------------------------------------------------------------------------
// K2: fused flash attention, DIRECT-GLOBAL operands (no LDS staging, no
// per-tile barriers — K/V are L2-hot: 512KB/head, ~1MB/XCD vs 4MB L2).
// 8 waves/block split-KV: group A (w<4) kv [0,1024), group B kv [1024,2048).
// Fragment addressing identical to the R3-verified direct path (+R6's vt
// permutation making V-frags 16B contiguous).
// ---------------------------------------------------------------------------
__global__ __launch_bounds__(512, 4) void mha_fused(
    const short* __restrict__ qb, const short* __restrict__ kb,
    const short* __restrict__ vt,
    float* __restrict__ wts, unsigned* __restrict__ attn)
{
    __shared__ float lx[512];
    __shared__ float sc[4096];     // 16 KB O-merge scratch

    const int bh = blockIdx.y;
    const int q0 = blockIdx.x * 64;
    const int t = threadIdx.x;
    const int w = t >> 6;          // 0..7
    const int grp = w >> 2;        // 0: kv [0,1024)  1: kv [1024,2048)
    const int wq = w & 3;          // q sub-tile
    const int lane = t & 63;
    const int g = lane >> 4;
    const int c = lane & 15;
    const int q = q0 + wq * 16 + c;

    const short* qrow = qb + ((size_t)bh * SEQ + q) * HD + 8 * g;
    const bf16x8 qf0 = *(const bf16x8*)(qrow);
    const bf16x8 qf1 = *(const bf16x8*)(qrow + 32);

    const short* kgb = kb + (size_t)bh * SEQ * HD;
    const short* vgb = vt + (size_t)bh * HD * SEQ;
    // per-lane fragment base pointers
    const short* kfb = kgb + (size_t)c * HD + 8 * g;      // + kt*64*HD + 16s*HD (+32)
    const short* vfb = vgb + (size_t)c * SEQ + 8 * g;     // + 16s*SEQ + kv0 (+32)

    const float scale2 = 0.125f * 1.44269504f;   // 1/sqrt(64) * log2(e)

    // ---- pass 1: row sums of exp2(s*scale2), each group over its half ---
    float l = 0.f;
    for (int ktl = 0; ktl < 16; ++ktl) {
        const int kt = ktl + grp * 16;
        const short* Kt = kfb + (size_t)kt * 64 * HD;
        bf16x8 kf[8];
#pragma unroll
        for (int s = 0; s < 4; ++s) {
            kf[2 * s]     = *(const bf16x8*)(Kt + (size_t)(16 * s) * HD);
            kf[2 * s + 1] = *(const bf16x8*)(Kt + (size_t)(16 * s) * HD + 32);
        }
        f32x4 a0 = {0.f,0.f,0.f,0.f}, a1 = {0.f,0.f,0.f,0.f};
        f32x4 a2 = {0.f,0.f,0.f,0.f}, a3 = {0.f,0.f,0.f,0.f};
        __builtin_amdgcn_s_setprio(1);
        a0 = __builtin_amdgcn_mfma_f32_16x16x32_bf16(kf[0], qf0, a0, 0, 0, 0);
        a0 = __builtin_amdgcn_mfma_f32_16x16x32_bf16(kf[1], qf1, a0, 0, 0, 0);
        a1 = __builtin_amdgcn_mfma_f32_16x16x32_bf16(kf[2], qf0, a1, 0, 0, 0);
        a1 = __builtin_amdgcn_mfma_f32_16x16x32_bf16(kf[3], qf1, a1, 0, 0, 0);
        a2 = __builtin_amdgcn_mfma_f32_16x16x32_bf16(kf[4], qf0, a2, 0, 0, 0);
        a2 = __builtin_amdgcn_mfma_f32_16x16x32_bf16(kf[5], qf1, a2, 0, 0, 0);
        a3 = __builtin_amdgcn_mfma_f32_16x16x32_bf16(kf[6], qf0, a3, 0, 0, 0);
        a3 = __builtin_amdgcn_mfma_f32_16x16x32_bf16(kf[7], qf1, a3, 0, 0, 0);
        __builtin_amdgcn_s_setprio(0);
        float ts = 0.f;
#pragma unroll
        for (int r = 0; r < 4; ++r) {
            ts += __builtin_amdgcn_exp2f(a0[r] * scale2);
            ts += __builtin_amdgcn_exp2f(a1[r] * scale2);
            ts += __builtin_amdgcn_exp2f(a2[r] * scale2);
            ts += __builtin_amdgcn_exp2f(a3[r] * scale2);
        }
        ts += __shfl_xor(ts, 16);
        ts += __shfl_xor(ts, 32);
        l += ts;
    }

    // merge l across partner waves (w ^ 4  <=>  t ^ 256)
    lx[t] = l;
    __syncthreads();
    l = lx[t] + lx[t ^ 256];
    const float c0 = -__builtin_amdgcn_logf(l);   // p = exp2(s*scale2 + c0)
    __syncthreads();

    // ---- pass 2: weights + PV over this group's half --------------------
    f32x4 o0 = {0.f,0.f,0.f,0.f}, o1 = {0.f,0.f,0.f,0.f};
    f32x4 o2 = {0.f,0.f,0.f,0.f}, o3 = {0.f,0.f,0.f,0.f};
    float* __restrict__ wrow = wts + ((size_t)bh * SEQ + q) * SEQ;

    for (int ktl = 0; ktl < 16; ++ktl) {
        const int kt = ktl + grp * 16;
        const int kv0 = kt * 64;
        const short* Kt = kfb + (size_t)kt * 64 * HD;
        bf16x8 kf[8];
#pragma unroll
        for (int s = 0; s < 4; ++s) {
            kf[2 * s]     = *(const bf16x8*)(Kt + (size_t)(16 * s) * HD);
            kf[2 * s + 1] = *(const bf16x8*)(Kt + (size_t)(16 * s) * HD + 32);
        }
        f32x4 a0 = {0.f,0.f,0.f,0.f}, a1 = {0.f,0.f,0.f,0.f};
        f32x4 a2 = {0.f,0.f,0.f,0.f}, a3 = {0.f,0.f,0.f,0.f};
        __builtin_amdgcn_s_setprio(1);
        a0 = __builtin_amdgcn_mfma_f32_16x16x32_bf16(kf[0], qf0, a0, 0, 0, 0);
        a0 = __builtin_amdgcn_mfma_f32_16x16x32_bf16(kf[1], qf1, a0, 0, 0, 0);
        a1 = __builtin_amdgcn_mfma_f32_16x16x32_bf16(kf[2], qf0, a1, 0, 0, 0);
        a1 = __builtin_amdgcn_mfma_f32_16x16x32_bf16(kf[3], qf1, a1, 0, 0, 0);
        a2 = __builtin_amdgcn_mfma_f32_16x16x32_bf16(kf[4], qf0, a2, 0, 0, 0);
        a2 = __builtin_amdgcn_mfma_f32_16x16x32_bf16(kf[5], qf1, a2, 0, 0, 0);
        a3 = __builtin_amdgcn_mfma_f32_16x16x32_bf16(kf[6], qf0, a3, 0, 0, 0);
        a3 = __builtin_amdgcn_mfma_f32_16x16x32_bf16(kf[7], qf1, a3, 0, 0, 0);
        __builtin_amdgcn_s_setprio(0);

        float pn[4][4];
#pragma unroll
        for (int r = 0; r < 4; ++r) {
            pn[0][r] = __builtin_amdgcn_exp2f(fmaf(a0[r], scale2, c0));
            pn[1][r] = __builtin_amdgcn_exp2f(fmaf(a1[r], scale2, c0));
            pn[2][r] = __builtin_amdgcn_exp2f(fmaf(a2[r], scale2, c0));
            pn[3][r] = __builtin_amdgcn_exp2f(fmaf(a3[r], scale2, c0));
        }
        // P pack by truncation (p >= 0; bias <= 2^-9 relative)
        union { bf16x8 v; unsigned u[4]; } pf0, pf1;
        pf0.u[0] = (__float_as_uint(pn[0][0]) >> 16) | (__float_as_uint(pn[0][1]) & 0xffff0000u);
        pf0.u[1] = (__float_as_uint(pn[0][2]) >> 16) | (__float_as_uint(pn[0][3]) & 0xffff0000u);
        pf0.u[2] = (__float_as_uint(pn[1][0]) >> 16) | (__float_as_uint(pn[1][1]) & 0xffff0000u);
        pf0.u[3] = (__float_as_uint(pn[1][2]) >> 16) | (__float_as_uint(pn[1][3]) & 0xffff0000u);
        pf1.u[0] = (__float_as_uint(pn[2][0]) >> 16) | (__float_as_uint(pn[2][1]) & 0xffff0000u);
        pf1.u[1] = (__float_as_uint(pn[2][2]) >> 16) | (__float_as_uint(pn[2][3]) & 0xffff0000u);
        pf1.u[2] = (__float_as_uint(pn[3][0]) >> 16) | (__float_as_uint(pn[3][1]) & 0xffff0000u);
        pf1.u[3] = (__float_as_uint(pn[3][2]) >> 16) | (__float_as_uint(pn[3][3]) & 0xffff0000u);

        const short* Vt = vfb + kv0;
        bf16x8 vf[8];
#pragma unroll
        for (int s = 0; s < 4; ++s) {
            vf[2 * s]     = *(const bf16x8*)(Vt + (size_t)(16 * s) * SEQ);
            vf[2 * s + 1] = *(const bf16x8*)(Vt + (size_t)(16 * s) * SEQ + 32);
        }
        __builtin_amdgcn_s_setprio(1);
        o0 = __builtin_amdgcn_mfma_f32_16x16x32_bf16(pf0.v, vf[0], o0, 0, 0, 0);
        o0 = __builtin_amdgcn_mfma_f32_16x16x32_bf16(pf1.v, vf[1], o0, 0, 0, 0);
        o1 = __builtin_amdgcn_mfma_f32_16x16x32_bf16(pf0.v, vf[2], o1, 0, 0, 0);
        o1 = __builtin_amdgcn_mfma_f32_16x16x32_bf16(pf1.v, vf[3], o1, 0, 0, 0);
        o2 = __builtin_amdgcn_mfma_f32_16x16x32_bf16(pf0.v, vf[4], o2, 0, 0, 0);
        o2 = __builtin_amdgcn_mfma_f32_16x16x32_bf16(pf1.v, vf[5], o2, 0, 0, 0);
        o3 = __builtin_amdgcn_mfma_f32_16x16x32_bf16(pf0.v, vf[6], o3, 0, 0, 0);
        o3 = __builtin_amdgcn_mfma_f32_16x16x32_bf16(pf1.v, vf[7], o3, 0, 0, 0);
        __builtin_amdgcn_s_setprio(0);

#pragma unroll
        for (int s = 0; s < 4; ++s) {
            float4 st;
            st.x = pn[s][0]; st.y = pn[s][1]; st.z = pn[s][2]; st.w = pn[s][3];
            *(float4*)(wrow + kv0 + 16 * s + 4 * g) = st;
        }
    }

    // ---- merge partial O across groups, write packed attn ---------------
    __syncthreads();   // lx reuse safety + group sync before merge
    if (w >= 4) {
        const int base = ((w - 4) * 64 + lane) * 16;
#pragma unroll
        for (int r = 0; r < 4; ++r) {
            sc[base + 0  + r] = o0[r];
            sc[base + 4  + r] = o1[r];
            sc[base + 8  + r] = o2[r];
            sc[base + 12 + r] = o3[r];
        }
    }
    __syncthreads();
    if (w < 4) {
        const int base = (w * 64 + lane) * 16;
        const size_t abase = ((size_t)bh * SEQ + q0 + 16 * w) * HD;
#pragma unroll
        for (int r = 0; r < 4; ++r) {
            const float v0 = o0[r] + sc[base + 0  + r];
            const float v1 = o1[r] + sc[base + 4  + r];
            const float v2 = o2[r] + sc[base + 8  + r];
            const float v3 = o3[r] + sc[base + 12 + r];
            const size_t ro = abase + (size_t)(4 * g + r) * HD + c;
            unsigned short h16, l16;
            h16 = f2bf(v0); l16 = f2bf(v0 - bf2f(h16));
            attn[ro +  0] = ((unsigned)h16 << 16) | l16;
            h16 = f2bf(v1); l16 = f2bf(v1 - bf2f(h16));
            attn[ro + 16] = ((unsigned)h16 << 16) | l16;
            h16 = f2bf(v2); l16 = f2bf(v2 - bf2f(h16));
            attn[ro + 32] = ((unsigned)h16 << 16) | l16;
            h16 = f2bf(v3); l16 = f2bf(v3 - bf2f(h16));
            attn[ro + 48] = ((unsigned)h16 << 16) | l16;
        }
    }
}

// ---------------------------------------------------------------------------
// K3: out = concat(attn) @ Wo + bo on MFMA (3-term split-bf16).
// A loaded as packed uint (hi<<16|lo), unpacked to two bf16x8 frags.
// ---------------------------------------------------------------------------
__global__ __launch_bounds__(256) void mha_oproj_mfma(
    const unsigned* __restrict__ attn, const unsigned short* __restrict__ wto,
    const float* __restrict__ bo, float* __restrict__ out)
{
    const int m0 = blockIdx.x * 32;
    const int n0 = blockIdx.y * 64;
    const int t = threadIdx.x;
    const int w = t >> 6;
    const int lane = t & 63;
    const int g = lane >> 4;
    const int c = lane & 15;
    const int wm = w & 1, wn = w >> 1;

    const int mrow = m0 + 16 * wm + c;
    const int b_ = mrow >> 11, sm = mrow & 2047;
    const unsigned* ab = attn + ((size_t)(b_ * NHEADS) * SEQ + sm) * HD + 8 * g;
    const short* wh = (const short*)wto + 8 * g;
    const short* wl = wh + (size_t)EMBED * EMBED;

    f32x4 acc[2];
    acc[0] = (f32x4){0.f, 0.f, 0.f, 0.f};
    acc[1] = (f32x4){0.f, 0.f, 0.f, 0.f};

#pragma unroll 4
    for (int ch = 0; ch < 16; ++ch) {
        const size_t aoff = (size_t)(ch >> 1) * SEQ * HD + (ch & 1) * 32;
        const uint4 ua = *(const uint4*)(ab + aoff);
        const uint4 ub = *(const uint4*)(ab + aoff + 4);
        union { bf16x8 v; unsigned short s[8]; } a_h, a_l;
        a_h.s[0] = (unsigned short)(ua.x >> 16); a_l.s[0] = (unsigned short)(ua.x & 0xffffu);
        a_h.s[1] = (unsigned short)(ua.y >> 16); a_l.s[1] = (unsigned short)(ua.y & 0xffffu);
        a_h.s[2] = (unsigned short)(ua.z >> 16); a_l.s[2] = (unsigned short)(ua.z & 0xffffu);
        a_h.s[3] = (unsigned short)(ua.w >> 16); a_l.s[3] = (unsigned short)(ua.w & 0xffffu);
        a_h.s[4] = (unsigned short)(ub.x >> 16); a_l.s[4] = (unsigned short)(ub.x & 0xffffu);
        a_h.s[5] = (unsigned short)(ub.y >> 16); a_l.s[5] = (unsigned short)(ub.y & 0xffffu);
        a_h.s[6] = (unsigned short)(ub.z >> 16); a_l.s[6] = (unsigned short)(ub.z & 0xffffu);
        a_h.s[7] = (unsigned short)(ub.w >> 16); a_l.s[7] = (unsigned short)(ub.w & 0xffffu);
#pragma unroll
        for (int s = 0; s < 2; ++s) {
            const int n = n0 + 32 * wn + 16 * s + c;
            const size_t woff = (size_t)n * EMBED + 32 * ch;
            const bf16x8 b_h = *(const bf16x8*)(wh + woff);
            const bf16x8 b_l = *(const bf16x8*)(wl + woff);
            acc[s] = __builtin_amdgcn_mfma_f32_16x16x32_bf16(a_h.v, b_h, acc[s], 0, 0, 0);
            acc[s] = __builtin_amdgcn_mfma_f32_16x16x32_bf16(a_l.v, b_h, acc[s], 0, 0, 0);
            acc[s] = __builtin_amdgcn_mfma_f32_16x16x32_bf16(a_h.v, b_l, acc[s], 0, 0, 0);
        }
    }

#pragma unroll
    for (int s = 0; s < 2; ++s) {
        const int n = n0 + 32 * wn + 16 * s + c;
        const float bb = bo[n];
#pragma unroll
        for (int r = 0; r < 4; ++r) {
            const int m = m0 + 16 * wm + 4 * g + r;
            out[(size_t)m * EMBED + n] = acc[s][r] + bb;
        }
    }
}

// ---------------------------------------------------------------------------
extern "C" void kernel_launch(void* const* d_in, const int* in_sizes, int n_in,
                              void* d_out, int out_size, void* d_ws, size_t ws_size,
                              hipStream_t stream)
{
    const float* x  = (const float*)d_in[0];
    const float* Wq = (const float*)d_in[1];
    const float* bq = (const float*)d_in[2];
    const float* Wk = (const float*)d_in[3];
    const float* bk = (const float*)d_in[4];
    const float* Wv = (const float*)d_in[5];
    const float* bv = (const float*)d_in[6];
    const float* Wo = (const float*)d_in[7];
    const float* bo = (const float*)d_in[8];

    float* out = (float*)d_out;                      // [2,2048,512]
    float* wts = out + (size_t)2 * SEQ * EMBED;      // [2,8,2048,2048]

    unsigned short* qbw = (unsigned short*)d_ws;             // bf16 [16][2048][64]
    unsigned short* kbw = qbw + (size_t)NBH * SEQ * HD;      // bf16 [16][2048][64]
    unsigned short* vtw = kbw + (size_t)NBH * SEQ * HD;      // bf16 [16][64][2048] (kv-permuted)
    unsigned* attn = (unsigned*)(vtw + (size_t)NBH * SEQ * HD);  // uint [16][2048][64]
    unsigned short* xh  = (unsigned short*)(attn + (size_t)NBH * SEQ * HD);
    unsigned short* xl  = xh + (size_t)MROWS * EMBED;        // bf16 [4096][512]
    unsigned short* wtw = xl + (size_t)MROWS * EMBED;        // bf16 [3][512][512]
    unsigned short* wto = wtw + (size_t)3 * EMBED * EMBED;   // bf16 [2][512][512]

    cvt_x<<<dim3(MROWS * EMBED / 4 / 256), 256, 0, stream>>>(x, xh, xl);
    cvt_w<<<dim3(8, 8, 5), 256, 0, stream>>>(Wq, Wk, Wv, Wo, wtw, wto);
    mha_qkv_mfma<<<dim3(64, 24), 256, 0, stream>>>(xh, xl, wtw, bq, bk, bv,
                                                   qbw, kbw, vtw);
    mha_fused  <<<dim3(32, NBH), 512, 0, stream>>>((const short*)qbw, (const short*)kbw,
                                                   (const short*)vtw, wts, attn);
    mha_oproj_mfma<<<dim3(128, 8), 256, 0, stream>>>(attn, wto, bo, out);
}

// Round 13
// 181.059 us; speedup vs baseline: 1.7396x; 1.7396x over previous
//
#include <hip/hip_runtime.h>
#include <cstddef>

#define EMBED 512
#define NHEADS 8
#define HD 64
#define SEQ 2048
#define NBH 16      // B * NHEADS
#define MROWS 4096  // B * SEQ

typedef __attribute__((ext_vector_type(8))) short bf16x8;
typedef __attribute__((ext_vector_type(4))) float f32x4;

__device__ __forceinline__ unsigned short f2bf(float x) {
    union { float f; unsigned u; } v; v.f = x;
    unsigned r = v.u + 0x7fffu + ((v.u >> 16) & 1u);
    return (unsigned short)(r >> 16);
}
__device__ __forceinline__ float bf2f(unsigned short u) {
    union { unsigned u; float f; } v; v.u = ((unsigned)u) << 16;
    return v.f;
}

// ---------------------------------------------------------------------------
// K0a: split x (fp32) into x_hi + x_lo (bf16 each).
// ---------------------------------------------------------------------------
__global__ __launch_bounds__(256) void cvt_x(
    const float* __restrict__ x, unsigned short* __restrict__ xh,
    unsigned short* __restrict__ xl)
{
    const int i = blockIdx.x * 256 + threadIdx.x;      // float4 index
    float4 v = ((const float4*)x)[i];
    ushort4 h, lo;
    h.x = f2bf(v.x); lo.x = f2bf(v.x - bf2f(h.x));
    h.y = f2bf(v.y); lo.y = f2bf(v.y - bf2f(h.y));
    h.z = f2bf(v.z); lo.z = f2bf(v.z - bf2f(h.z));
    h.w = f2bf(v.w); lo.w = f2bf(v.w - bf2f(h.w));
    ((ushort4*)xh)[i] = h;
    ((ushort4*)xl)[i] = lo;
}

// ---------------------------------------------------------------------------
// K0b: Wq/Wk/Wv transposed to bf16: wt[z][n][k].  grid (8,8,3).
// ---------------------------------------------------------------------------
__global__ __launch_bounds__(256) void cvt_w(
    const float* __restrict__ Wq, const float* __restrict__ Wk,
    const float* __restrict__ Wv, unsigned short* __restrict__ wt)
{
    __shared__ float Ws[64][65];
    const int z = blockIdx.z;
    const float* __restrict__ W = (z == 0) ? Wq : (z == 1) ? Wk : Wv;
    const int k0 = blockIdx.x * 64, n0 = blockIdx.y * 64;
    const int t = threadIdx.x;
#pragma unroll
    for (int l = 0; l < 4; ++l) {
        const int idx = t + 256 * l;
        const int r = idx >> 4, c4 = (idx & 15) * 4;
        float4 w = *(const float4*)(W + (size_t)(k0 + r) * EMBED + n0 + c4);
        Ws[r][c4 + 0] = w.x; Ws[r][c4 + 1] = w.y;
        Ws[r][c4 + 2] = w.z; Ws[r][c4 + 3] = w.w;
    }
    __syncthreads();
    unsigned short* __restrict__ dst = wt + (size_t)z * EMBED * EMBED;
#pragma unroll
    for (int l = 0; l < 4; ++l) {
        const int idx = t + 256 * l;
        const int rn = idx >> 4, k4 = (idx & 15) * 4;
        ushort4 o;
        o.x = f2bf(Ws[k4 + 0][rn]);
        o.y = f2bf(Ws[k4 + 1][rn]);
        o.z = f2bf(Ws[k4 + 2][rn]);
        o.w = f2bf(Ws[k4 + 3][rn]);
        *(ushort4*)(dst + (size_t)(n0 + rn) * EMBED + k0 + k4) = o;
    }
}

// ---------------------------------------------------------------------------
// K1: QKV projection on MFMA.  out = (x_hi + x_lo) @ W_z + b_z, bf16 out.
// v written to vt with per-32 kv permutation (so PV B-frags are 16B).
// ---------------------------------------------------------------------------
__global__ __launch_bounds__(256) void mha_qkv_mfma(
    const unsigned short* __restrict__ xh, const unsigned short* __restrict__ xl,
    const unsigned short* __restrict__ wt,
    const float* __restrict__ bq, const float* __restrict__ bk,
    const float* __restrict__ bv,
    unsigned short* __restrict__ qo, unsigned short* __restrict__ ko,
    unsigned short* __restrict__ vt)
{
    const int m0 = blockIdx.x * 64;
    const int z  = blockIdx.y >> 3;
    const int n0 = (blockIdx.y & 7) * 64;
    const float* __restrict__ bias = (z == 0) ? bq : (z == 1) ? bk : bv;

    const int t = threadIdx.x;
    const int w = t >> 6;
    const int lane = t & 63;
    const int g = lane >> 4;
    const int c = lane & 15;

    const short* ah_row = (const short*)xh + (size_t)(m0 + 16 * w + c) * EMBED + 8 * g;
    const short* al_row = (const short*)xl + (size_t)(m0 + 16 * w + c) * EMBED + 8 * g;
    const short* wz = (const short*)wt + (size_t)z * EMBED * EMBED + 8 * g;

    f32x4 acc[4];
#pragma unroll
    for (int s = 0; s < 4; ++s) acc[s] = (f32x4){0.f, 0.f, 0.f, 0.f};

#pragma unroll 4
    for (int ch = 0; ch < 16; ++ch) {
        const int k0 = ch * 32;
        const bf16x8 ah = *(const bf16x8*)(ah_row + k0);
        const bf16x8 al = *(const bf16x8*)(al_row + k0);
#pragma unroll
        for (int s = 0; s < 4; ++s) {
            const bf16x8 bs = *(const bf16x8*)(wz + (size_t)(n0 + 16 * s + c) * EMBED + k0);
            acc[s] = __builtin_amdgcn_mfma_f32_16x16x32_bf16(ah, bs, acc[s], 0, 0, 0);
            acc[s] = __builtin_amdgcn_mfma_f32_16x16x32_bf16(al, bs, acc[s], 0, 0, 0);
        }
    }

    if (z < 2) {
        unsigned short* __restrict__ out = (z == 0) ? qo : ko;
#pragma unroll
        for (int s = 0; s < 4; ++s) {
            const int n = n0 + 16 * s + c;
            const int h = n >> 6, d = n & 63;
            const float bb = bias[n];
#pragma unroll
            for (int r = 0; r < 4; ++r) {
                const int m  = m0 + 16 * w + 4 * g + r;
                const int b_ = m >> 11, sm = m & 2047;
                out[((size_t)(b_ * NHEADS + h) * SEQ + sm) * HD + d] =
                    f2bf(acc[s][r] + bb);
            }
        }
    } else {
        const int m  = m0 + 16 * w + 4 * g;     // base kv of the 4-row chunk
        const int b_ = m >> 11, sm = m & 2047;
        const int a  = sm >> 5, rem = sm & 31;
        const int pos = 32 * a + 8 * ((rem & 15) >> 2) + ((rem >> 4) << 2);
        const int h  = n0 >> 6;
#pragma unroll
        for (int s = 0; s < 4; ++s) {
            const int d = 16 * s + c;
            const float bb = bias[n0 + d];
            ushort4 o;
            o.x = f2bf(acc[s][0] + bb);
            o.y = f2bf(acc[s][1] + bb);
            o.z = f2bf(acc[s][2] + bb);
            o.w = f2bf(acc[s][3] + bb);
            *(ushort4*)(vt + ((size_t)(b_ * NHEADS + h) * HD + d) * SEQ + pos) = o;
        }
    }
}

// ---------------------------------------------------------------------------
// K2: fused flash attention (R11 structure: SPLIT-KV, 8 waves/block, K/V
// LDS-staged XOR-swizzled double-buffered; group A kv [0,1024), group B
// [1024,2048); l merged via LDS; partial O merged via LDS).
// O written as plain fp32 attn (for the fp32 LDS out-projection).
// ---------------------------------------------------------------------------
__global__ __launch_bounds__(512, 4) void mha_fused(
    const short* __restrict__ qb, const short* __restrict__ kb,
    const short* __restrict__ vt,
    float* __restrict__ wts, float* __restrict__ attn)
{
    __shared__ short KsA[2][4096];
    __shared__ short VsA[2][4096];
    __shared__ short KsB[2][4096];
    __shared__ short VsB[2][4096];
    __shared__ float lx[512];

    const int bh = blockIdx.y;
    const int q0 = blockIdx.x * 64;
    const int t = threadIdx.x;
    const int w = t >> 6;          // 0..7
    const int grp = w >> 2;        // 0: kv [0,1024)  1: kv [1024,2048)
    const int wq = w & 3;          // q sub-tile
    const int lane = t & 63;
    const int g = lane >> 4;
    const int c = lane & 15;
    const int q = q0 + wq * 16 + c;

    const short* qrow = qb + ((size_t)bh * SEQ + q) * HD + 8 * g;
    const bf16x8 qf0 = *(const bf16x8*)(qrow);
    const bf16x8 qf1 = *(const bf16x8*)(qrow + 32);

    // staging: one 16B chunk per thread per 8KB tile
    const int rs = t >> 3, bls = t & 7;
    const int dss = rs * 64 + ((bls ^ (rs & 7)) << 3);
    const short* kgb = kb + (size_t)bh * SEQ * HD;
    const short* vgb = vt + (size_t)bh * HD * SEQ;

    int koff[4][2];
#pragma unroll
    for (int s = 0; s < 4; ++s) {
        const int rr = c + 16 * s;
        koff[s][0] = rr * 64 + (((g    ) ^ (rr & 7)) << 3);
        koff[s][1] = rr * 64 + (((g + 4) ^ (rr & 7)) << 3);
    }
    int voff2[4][2];
#pragma unroll
    for (int s = 0; s < 4; ++s) {
        const int rv = 16 * s + c;
        voff2[s][0] = rv * 64 + (((g    ) ^ (rv & 7)) << 3);
        voff2[s][1] = rv * 64 + (((g + 4) ^ (rv & 7)) << 3);
    }

    const float scale2 = 0.125f * 1.44269504f;   // 1/sqrt(64) * log2(e)

    // ---- pass 1: row sums of exp2(s*scale2), each group over its half ---
    float l = 0.f;

    auto sum_tile = [&](const short* Kb) {
        f32x4 a0 = {0.f,0.f,0.f,0.f}, a1 = {0.f,0.f,0.f,0.f};
        f32x4 a2 = {0.f,0.f,0.f,0.f}, a3 = {0.f,0.f,0.f,0.f};
        __builtin_amdgcn_s_setprio(1);
        a0 = __builtin_amdgcn_mfma_f32_16x16x32_bf16(*(const bf16x8*)(Kb + koff[0][0]), qf0, a0, 0, 0, 0);
        a0 = __builtin_amdgcn_mfma_f32_16x16x32_bf16(*(const bf16x8*)(Kb + koff[0][1]), qf1, a0, 0, 0, 0);
        a1 = __builtin_amdgcn_mfma_f32_16x16x32_bf16(*(const bf16x8*)(Kb + koff[1][0]), qf0, a1, 0, 0, 0);
        a1 = __builtin_amdgcn_mfma_f32_16x16x32_bf16(*(const bf16x8*)(Kb + koff[1][1]), qf1, a1, 0, 0, 0);
        a2 = __builtin_amdgcn_mfma_f32_16x16x32_bf16(*(const bf16x8*)(Kb + koff[2][0]), qf0, a2, 0, 0, 0);
        a2 = __builtin_amdgcn_mfma_f32_16x16x32_bf16(*(const bf16x8*)(Kb + koff[2][1]), qf1, a2, 0, 0, 0);
        a3 = __builtin_amdgcn_mfma_f32_16x16x32_bf16(*(const bf16x8*)(Kb + koff[3][0]), qf0, a3, 0, 0, 0);
        a3 = __builtin_amdgcn_mfma_f32_16x16x32_bf16(*(const bf16x8*)(Kb + koff[3][1]), qf1, a3, 0, 0, 0);
        __builtin_amdgcn_s_setprio(0);
        float ts = 0.f;
#pragma unroll
        for (int r = 0; r < 4; ++r) {
            ts += __builtin_amdgcn_exp2f(a0[r] * scale2);
            ts += __builtin_amdgcn_exp2f(a1[r] * scale2);
            ts += __builtin_amdgcn_exp2f(a2[r] * scale2);
            ts += __builtin_amdgcn_exp2f(a3[r] * scale2);
        }
        ts += __shfl_xor(ts, 16);
        ts += __shfl_xor(ts, 32);
        l += ts;
    };

    {   // prologue: stage local tile 0 of both groups
        uint4 kA = *(const uint4*)(kgb + (size_t)0  * 64 * HD + (size_t)t * 8);
        uint4 kB = *(const uint4*)(kgb + (size_t)16 * 64 * HD + (size_t)t * 8);
        *(uint4*)(&KsA[0][dss]) = kA;
        *(uint4*)(&KsB[0][dss]) = kB;
    }
    __syncthreads();
    int cur = 0;
    for (int ktl = 0; ktl < 16; ++ktl) {
        uint4 nA, nB;
        if (ktl < 15) {
            nA = *(const uint4*)(kgb + (size_t)(ktl + 1)  * 64 * HD + (size_t)t * 8);
            nB = *(const uint4*)(kgb + (size_t)(ktl + 17) * 64 * HD + (size_t)t * 8);
        }
        sum_tile(grp ? &KsB[cur][0] : &KsA[cur][0]);
        if (ktl < 15) {
            *(uint4*)(&KsA[cur ^ 1][dss]) = nA;
            *(uint4*)(&KsB[cur ^ 1][dss]) = nB;
        }
        __syncthreads();
        cur ^= 1;
    }

    // merge l across partner waves (w ^ 4  <=>  t ^ 256)
    lx[t] = l;
    __syncthreads();
    l = lx[t] + lx[t ^ 256];
    const float c0 = -__builtin_amdgcn_logf(l);   // p = exp2(s*scale2 + c0)
    __syncthreads();

    // ---- pass 2: weights + PV over this group's half --------------------
    f32x4 o0 = {0.f,0.f,0.f,0.f}, o1 = {0.f,0.f,0.f,0.f};
    f32x4 o2 = {0.f,0.f,0.f,0.f}, o3 = {0.f,0.f,0.f,0.f};
    float* __restrict__ wrow = wts + ((size_t)bh * SEQ + q) * SEQ;

    auto pv_tile = [&](const short* Kb, const short* Vb, int kv0) {
        f32x4 a0 = {0.f,0.f,0.f,0.f}, a1 = {0.f,0.f,0.f,0.f};
        f32x4 a2 = {0.f,0.f,0.f,0.f}, a3 = {0.f,0.f,0.f,0.f};
        __builtin_amdgcn_s_setprio(1);
        a0 = __builtin_amdgcn_mfma_f32_16x16x32_bf16(*(const bf16x8*)(Kb + koff[0][0]), qf0, a0, 0, 0, 0);
        a0 = __builtin_amdgcn_mfma_f32_16x16x32_bf16(*(const bf16x8*)(Kb + koff[0][1]), qf1, a0, 0, 0, 0);
        a1 = __builtin_amdgcn_mfma_f32_16x16x32_bf16(*(const bf16x8*)(Kb + koff[1][0]), qf0, a1, 0, 0, 0);
        a1 = __builtin_amdgcn_mfma_f32_16x16x32_bf16(*(const bf16x8*)(Kb + koff[1][1]), qf1, a1, 0, 0, 0);
        a2 = __builtin_amdgcn_mfma_f32_16x16x32_bf16(*(const bf16x8*)(Kb + koff[2][0]), qf0, a2, 0, 0, 0);
        a2 = __builtin_amdgcn_mfma_f32_16x16x32_bf16(*(const bf16x8*)(Kb + koff[2][1]), qf1, a2, 0, 0, 0);
        a3 = __builtin_amdgcn_mfma_f32_16x16x32_bf16(*(const bf16x8*)(Kb + koff[3][0]), qf0, a3, 0, 0, 0);
        a3 = __builtin_amdgcn_mfma_f32_16x16x32_bf16(*(const bf16x8*)(Kb + koff[3][1]), qf1, a3, 0, 0, 0);
        __builtin_amdgcn_s_setprio(0);

        float pn[4][4];
#pragma unroll
        for (int r = 0; r < 4; ++r) {
            pn[0][r] = __builtin_amdgcn_exp2f(fmaf(a0[r], scale2, c0));
            pn[1][r] = __builtin_amdgcn_exp2f(fmaf(a1[r], scale2, c0));
            pn[2][r] = __builtin_amdgcn_exp2f(fmaf(a2[r], scale2, c0));
            pn[3][r] = __builtin_amdgcn_exp2f(fmaf(a3[r], scale2, c0));
        }
        // P pack by truncation (p >= 0; bias <= 2^-9 relative)
        union { bf16x8 v; unsigned u[4]; } pf0, pf1;
        pf0.u[0] = (__float_as_uint(pn[0][0]) >> 16) | (__float_as_uint(pn[0][1]) & 0xffff0000u);
        pf0.u[1] = (__float_as_uint(pn[0][2]) >> 16) | (__float_as_uint(pn[0][3]) & 0xffff0000u);
        pf0.u[2] = (__float_as_uint(pn[1][0]) >> 16) | (__float_as_uint(pn[1][1]) & 0xffff0000u);
        pf0.u[3] = (__float_as_uint(pn[1][2]) >> 16) | (__float_as_uint(pn[1][3]) & 0xffff0000u);
        pf1.u[0] = (__float_as_uint(pn[2][0]) >> 16) | (__float_as_uint(pn[2][1]) & 0xffff0000u);
        pf1.u[1] = (__float_as_uint(pn[2][2]) >> 16) | (__float_as_uint(pn[2][3]) & 0xffff0000u);
        pf1.u[2] = (__float_as_uint(pn[3][0]) >> 16) | (__float_as_uint(pn[3][1]) & 0xffff0000u);
        pf1.u[3] = (__float_as_uint(pn[3][2]) >> 16) | (__float_as_uint(pn[3][3]) & 0xffff0000u);

        __builtin_amdgcn_s_setprio(1);
#pragma unroll
        for (int sub = 0; sub < 4; ++sub) {
            const bf16x8 vf0 = *(const bf16x8*)(Vb + voff2[sub][0]);
            const bf16x8 vf1 = *(const bf16x8*)(Vb + voff2[sub][1]);
            f32x4& o = (sub == 0) ? o0 : (sub == 1) ? o1 : (sub == 2) ? o2 : o3;
            o = __builtin_amdgcn_mfma_f32_16x16x32_bf16(pf0.v, vf0, o, 0, 0, 0);
            o = __builtin_amdgcn_mfma_f32_16x16x32_bf16(pf1.v, vf1, o, 0, 0, 0);
        }
        __builtin_amdgcn_s_setprio(0);
#pragma unroll
        for (int s = 0; s < 4; ++s) {
            float4 st;
            st.x = pn[s][0]; st.y = pn[s][1]; st.z = pn[s][2]; st.w = pn[s][3];
            *(float4*)(wrow + kv0 + 16 * s + 4 * g) = st;
        }
    };

    {   // prologue: stage K and V local tile 0 of both groups
        uint4 kA = *(const uint4*)(kgb + (size_t)0  * 64 * HD + (size_t)t * 8);
        uint4 kB = *(const uint4*)(kgb + (size_t)16 * 64 * HD + (size_t)t * 8);
        uint4 vA = *(const uint4*)(vgb + (size_t)rs * SEQ + 0    + bls * 8);
        uint4 vB = *(const uint4*)(vgb + (size_t)rs * SEQ + 1024 + bls * 8);
        *(uint4*)(&KsA[0][dss]) = kA;  *(uint4*)(&KsB[0][dss]) = kB;
        *(uint4*)(&VsA[0][dss]) = vA;  *(uint4*)(&VsB[0][dss]) = vB;
    }
    __syncthreads();
    cur = 0;
    for (int ktl = 0; ktl < 16; ++ktl) {
        uint4 nKA, nKB, nVA, nVB;
        if (ktl < 15) {
            nKA = *(const uint4*)(kgb + (size_t)(ktl + 1)  * 64 * HD + (size_t)t * 8);
            nKB = *(const uint4*)(kgb + (size_t)(ktl + 17) * 64 * HD + (size_t)t * 8);
            nVA = *(const uint4*)(vgb + (size_t)rs * SEQ + (ktl + 1)  * 64 + bls * 8);
            nVB = *(const uint4*)(vgb + (size_t)rs * SEQ + (ktl + 17) * 64 + bls * 8);
        }
        if (grp == 0) pv_tile(&KsA[cur][0], &VsA[cur][0], ktl * 64);
        else          pv_tile(&KsB[cur][0], &VsB[cur][0], 1024 + ktl * 64);
        if (ktl < 15) {
            *(uint4*)(&KsA[cur ^ 1][dss]) = nKA;  *(uint4*)(&KsB[cur ^ 1][dss]) = nKB;
            *(uint4*)(&VsA[cur ^ 1][dss]) = nVA;  *(uint4*)(&VsB[cur ^ 1][dss]) = nVB;
        }
        __syncthreads();
        cur ^= 1;
    }

    // ---- merge partial O across groups, write fp32 attn -----------------
    float* sc = (float*)&KsA[0][0];   // 16 KB scratch (KsA region, done with)
    if (w >= 4) {
        const int base = ((w - 4) * 64 + lane) * 16;
#pragma unroll
        for (int r = 0; r < 4; ++r) {
            sc[base + 0  + r] = o0[r];
            sc[base + 4  + r] = o1[r];
            sc[base + 8  + r] = o2[r];
            sc[base + 12 + r] = o3[r];
        }
    }
    __syncthreads();
    if (w < 4) {
        const int base = (w * 64 + lane) * 16;
        const size_t abase = ((size_t)bh * SEQ + q0 + 16 * w) * HD;
#pragma unroll
        for (int r = 0; r < 4; ++r) {
            const size_t ro = abase + (size_t)(4 * g + r) * HD + c;
            attn[ro +  0] = o0[r] + sc[base + 0  + r];
            attn[ro + 16] = o1[r] + sc[base + 4  + r];
            attn[ro + 32] = o2[r] + sc[base + 8  + r];
            attn[ro + 48] = o3[r] + sc[base + 12 + r];
        }
    }
}

// ---------------------------------------------------------------------------
// K3: out = concat(attn) @ Wo + bo.  fp32, LDS-staged 64x64x64, 4x4 micro
// (R5's proven version).  grid (64, 8).
// ---------------------------------------------------------------------------
__global__ __launch_bounds__(256) void mha_oproj(
    const float* __restrict__ attn,
    const float* __restrict__ Wo, const float* __restrict__ bo,
    float* __restrict__ out)
{
    __shared__ float As[64][68];
    __shared__ float Bs[64][68];
    const int m0 = blockIdx.x * 64;
    const int n0 = blockIdx.y * 64;
    const int t  = threadIdx.x;
    const int tx = t & 15, ty = t >> 4;

    float acc[4][4];
#pragma unroll
    for (int i = 0; i < 4; ++i)
#pragma unroll
        for (int j = 0; j < 4; ++j) acc[i][j] = 0.f;

    for (int k0 = 0; k0 < EMBED; k0 += 64) {
        const int h = k0 >> 6;
#pragma unroll
        for (int l = 0; l < 4; ++l) {
            const int f = t + 256 * l;
            const int r = f >> 4, ck = (f & 15) * 4;
            const int mm = m0 + r;
            const int b_ = mm >> 11, s = mm & 2047;
            *(float4*)&As[r][ck] =
                *(const float4*)(attn + ((size_t)(b_ * NHEADS + h) * SEQ + s) * HD + ck);
        }
#pragma unroll
        for (int l = 0; l < 4; ++l) {
            const int f = t + 256 * l;
            const int r = f >> 4, cc = (f & 15) * 4;
            *(float4*)&Bs[r][cc] = *(const float4*)(Wo + (size_t)(k0 + r) * EMBED + n0 + cc);
        }
        __syncthreads();
#pragma unroll
        for (int u = 0; u < 16; ++u) {
            const int kk = u * 4;
            float4 av[4], bv[4];
#pragma unroll
            for (int i = 0; i < 4; ++i)
                av[i] = *(const float4*)&As[ty * 4 + i][kk];
#pragma unroll
            for (int j = 0; j < 4; ++j)
                bv[j] = *(const float4*)&Bs[kk + j][tx * 4];
#pragma unroll
            for (int i = 0; i < 4; ++i) {
                acc[i][0] = fmaf(av[i].x, bv[0].x, acc[i][0]);
                acc[i][1] = fmaf(av[i].x, bv[0].y, acc[i][1]);
                acc[i][2] = fmaf(av[i].x, bv[0].z, acc[i][2]);
                acc[i][3] = fmaf(av[i].x, bv[0].w, acc[i][3]);
                acc[i][0] = fmaf(av[i].y, bv[1].x, acc[i][0]);
                acc[i][1] = fmaf(av[i].y, bv[1].y, acc[i][1]);
                acc[i][2] = fmaf(av[i].y, bv[1].z, acc[i][2]);
                acc[i][3] = fmaf(av[i].y, bv[1].w, acc[i][3]);
                acc[i][0] = fmaf(av[i].z, bv[2].x, acc[i][0]);
                acc[i][1] = fmaf(av[i].z, bv[2].y, acc[i][1]);
                acc[i][2] = fmaf(av[i].z, bv[2].z, acc[i][2]);
                acc[i][3] = fmaf(av[i].z, bv[2].w, acc[i][3]);
                acc[i][0] = fmaf(av[i].w, bv[3].x, acc[i][0]);
                acc[i][1] = fmaf(av[i].w, bv[3].y, acc[i][1]);
                acc[i][2] = fmaf(av[i].w, bv[3].z, acc[i][2]);
                acc[i][3] = fmaf(av[i].w, bv[3].w, acc[i][3]);
            }
        }
        __syncthreads();
    }

#pragma unroll
    for (int i = 0; i < 4; ++i) {
        const int mm = m0 + ty * 4 + i;
        const int n  = n0 + tx * 4;
        float4 r;
        r.x = acc[i][0] + bo[n + 0];
        r.y = acc[i][1] + bo[n + 1];
        r.z = acc[i][2] + bo[n + 2];
        r.w = acc[i][3] + bo[n + 3];
        *(float4*)(out + (size_t)mm * EMBED + n) = r;
    }
}

// ---------------------------------------------------------------------------
extern "C" void kernel_launch(void* const* d_in, const int* in_sizes, int n_in,
                              void* d_out, int out_size, void* d_ws, size_t ws_size,
                              hipStream_t stream)
{
    const float* x  = (const float*)d_in[0];
    const float* Wq = (const float*)d_in[1];
    const float* bq = (const float*)d_in[2];
    const float* Wk = (const float*)d_in[3];
    const float* bk = (const float*)d_in[4];
    const float* Wv = (const float*)d_in[5];
    const float* bv = (const float*)d_in[6];
    const float* Wo = (const float*)d_in[7];
    const float* bo = (const float*)d_in[8];

    float* out = (float*)d_out;                      // [2,2048,512]
    float* wts = out + (size_t)2 * SEQ * EMBED;      // [2,8,2048,2048]

    unsigned short* qbw = (unsigned short*)d_ws;             // bf16 [16][2048][64]
    unsigned short* kbw = qbw + (size_t)NBH * SEQ * HD;      // bf16 [16][2048][64]
    unsigned short* vtw = kbw + (size_t)NBH * SEQ * HD;      // bf16 [16][64][2048] (kv-permuted)
    float* attn = (float*)(vtw + (size_t)NBH * SEQ * HD);    // fp32 [16][2048][64]
    unsigned short* xh  = (unsigned short*)(attn + (size_t)NBH * SEQ * HD);
    unsigned short* xl  = xh + (size_t)MROWS * EMBED;        // bf16 [4096][512]
    unsigned short* wtw = xl + (size_t)MROWS * EMBED;        // bf16 [3][512][512]

    cvt_x<<<dim3(MROWS * EMBED / 4 / 256), 256, 0, stream>>>(x, xh, xl);
    cvt_w<<<dim3(8, 8, 3), 256, 0, stream>>>(Wq, Wk, Wv, wtw);
    mha_qkv_mfma<<<dim3(64, 24), 256, 0, stream>>>(xh, xl, wtw, bq, bk, bv,
                                                   qbw, kbw, vtw);
    mha_fused  <<<dim3(32, NBH), 512, 0, stream>>>((const short*)qbw, (const short*)kbw,
                                                   (const short*)vtw, wts, attn);
    mha_oproj  <<<dim3(64, 8), 256, 0, stream>>>(attn, Wo, bo, out);
}

// Round 14
// 164.892 us; speedup vs baseline: 1.9101x; 1.0980x over previous
//
#include <hip/hip_runtime.h>
#include <cstddef>

#define EMBED 512
#define NHEADS 8
#define HD 64
#define SEQ 2048
#define NBH 16      // B * NHEADS
#define MROWS 4096  // B * SEQ

typedef __attribute__((ext_vector_type(8))) short bf16x8;
typedef __attribute__((ext_vector_type(4))) float f32x4;

__device__ __forceinline__ unsigned short f2bf(float x) {
    union { float f; unsigned u; } v; v.f = x;
    unsigned r = v.u + 0x7fffu + ((v.u >> 16) & 1u);
    return (unsigned short)(r >> 16);
}
__device__ __forceinline__ float bf2f(unsigned short u) {
    union { unsigned u; float f; } v; v.u = ((unsigned)u) << 16;
    return v.f;
}

// ---------------------------------------------------------------------------
// K0a: split x (fp32) into x_hi + x_lo (bf16 each).
// ---------------------------------------------------------------------------
__global__ __launch_bounds__(256) void cvt_x(
    const float* __restrict__ x, unsigned short* __restrict__ xh,
    unsigned short* __restrict__ xl)
{
    const int i = blockIdx.x * 256 + threadIdx.x;      // float4 index
    float4 v = ((const float4*)x)[i];
    ushort4 h, lo;
    h.x = f2bf(v.x); lo.x = f2bf(v.x - bf2f(h.x));
    h.y = f2bf(v.y); lo.y = f2bf(v.y - bf2f(h.y));
    h.z = f2bf(v.z); lo.z = f2bf(v.z - bf2f(h.z));
    h.w = f2bf(v.w); lo.w = f2bf(v.w - bf2f(h.w));
    ((ushort4*)xh)[i] = h;
    ((ushort4*)xl)[i] = lo;
}

// ---------------------------------------------------------------------------
// K0b: weight transposes to bf16.  z=0..2: Wq/Wk/Wv -> wt[z][n][k] (hi only).
// z=3: Wo hi -> wto[0];  z=4: Wo lo -> wto[1].
// ---------------------------------------------------------------------------
__global__ __launch_bounds__(256) void cvt_w(
    const float* __restrict__ Wq, const float* __restrict__ Wk,
    const float* __restrict__ Wv, const float* __restrict__ Wo,
    unsigned short* __restrict__ wt, unsigned short* __restrict__ wto)
{
    __shared__ float Ws[64][65];
    const int z = blockIdx.z;
    const float* __restrict__ W = (z == 0) ? Wq : (z == 1) ? Wk : (z == 2) ? Wv : Wo;
    const int k0 = blockIdx.x * 64, n0 = blockIdx.y * 64;
    const int t = threadIdx.x;
#pragma unroll
    for (int l = 0; l < 4; ++l) {
        const int idx = t + 256 * l;
        const int r = idx >> 4, c4 = (idx & 15) * 4;
        float4 w = *(const float4*)(W + (size_t)(k0 + r) * EMBED + n0 + c4);
        Ws[r][c4 + 0] = w.x; Ws[r][c4 + 1] = w.y;
        Ws[r][c4 + 2] = w.z; Ws[r][c4 + 3] = w.w;
    }
    __syncthreads();
    unsigned short* __restrict__ dst =
        (z < 3) ? (wt + (size_t)z * EMBED * EMBED)
                : (wto + (size_t)(z - 3) * EMBED * EMBED);
#pragma unroll
    for (int l = 0; l < 4; ++l) {
        const int idx = t + 256 * l;
        const int rn = idx >> 4, k4 = (idx & 15) * 4;
        ushort4 o;
        if (z == 4) {
            float v0 = Ws[k4 + 0][rn], v1 = Ws[k4 + 1][rn];
            float v2 = Ws[k4 + 2][rn], v3 = Ws[k4 + 3][rn];
            o.x = f2bf(v0 - bf2f(f2bf(v0)));
            o.y = f2bf(v1 - bf2f(f2bf(v1)));
            o.z = f2bf(v2 - bf2f(f2bf(v2)));
            o.w = f2bf(v3 - bf2f(f2bf(v3)));
        } else {
            o.x = f2bf(Ws[k4 + 0][rn]);
            o.y = f2bf(Ws[k4 + 1][rn]);
            o.z = f2bf(Ws[k4 + 2][rn]);
            o.w = f2bf(Ws[k4 + 3][rn]);
        }
        *(ushort4*)(dst + (size_t)(n0 + rn) * EMBED + k0 + k4) = o;
    }
}

// ---------------------------------------------------------------------------
// K1: QKV projection on MFMA.  out = (x_hi + x_lo) @ W_z + b_z, bf16 out.
// v written to vt with per-32 kv permutation (so PV B-frags are 16B).
// ---------------------------------------------------------------------------
__global__ __launch_bounds__(256) void mha_qkv_mfma(
    const unsigned short* __restrict__ xh, const unsigned short* __restrict__ xl,
    const unsigned short* __restrict__ wt,
    const float* __restrict__ bq, const float* __restrict__ bk,
    const float* __restrict__ bv,
    unsigned short* __restrict__ qo, unsigned short* __restrict__ ko,
    unsigned short* __restrict__ vt)
{
    const int m0 = blockIdx.x * 64;
    const int z  = blockIdx.y >> 3;
    const int n0 = (blockIdx.y & 7) * 64;
    const float* __restrict__ bias = (z == 0) ? bq : (z == 1) ? bk : bv;

    const int t = threadIdx.x;
    const int w = t >> 6;
    const int lane = t & 63;
    const int g = lane >> 4;
    const int c = lane & 15;

    const short* ah_row = (const short*)xh + (size_t)(m0 + 16 * w + c) * EMBED + 8 * g;
    const short* al_row = (const short*)xl + (size_t)(m0 + 16 * w + c) * EMBED + 8 * g;
    const short* wz = (const short*)wt + (size_t)z * EMBED * EMBED + 8 * g;

    f32x4 acc[4];
#pragma unroll
    for (int s = 0; s < 4; ++s) acc[s] = (f32x4){0.f, 0.f, 0.f, 0.f};

#pragma unroll 4
    for (int ch = 0; ch < 16; ++ch) {
        const int k0 = ch * 32;
        const bf16x8 ah = *(const bf16x8*)(ah_row + k0);
        const bf16x8 al = *(const bf16x8*)(al_row + k0);
#pragma unroll
        for (int s = 0; s < 4; ++s) {
            const bf16x8 bs = *(const bf16x8*)(wz + (size_t)(n0 + 16 * s + c) * EMBED + k0);
            acc[s] = __builtin_amdgcn_mfma_f32_16x16x32_bf16(ah, bs, acc[s], 0, 0, 0);
            acc[s] = __builtin_amdgcn_mfma_f32_16x16x32_bf16(al, bs, acc[s], 0, 0, 0);
        }
    }

    if (z < 2) {
        unsigned short* __restrict__ out = (z == 0) ? qo : ko;
#pragma unroll
        for (int s = 0; s < 4; ++s) {
            const int n = n0 + 16 * s + c;
            const int h = n >> 6, d = n & 63;
            const float bb = bias[n];
#pragma unroll
            for (int r = 0; r < 4; ++r) {
                const int m  = m0 + 16 * w + 4 * g + r;
                const int b_ = m >> 11, sm = m & 2047;
                out[((size_t)(b_ * NHEADS + h) * SEQ + sm) * HD + d] =
                    f2bf(acc[s][r] + bb);
            }
        }
    } else {
        const int m  = m0 + 16 * w + 4 * g;     // base kv of the 4-row chunk
        const int b_ = m >> 11, sm = m & 2047;
        const int a  = sm >> 5, rem = sm & 31;
        const int pos = 32 * a + 8 * ((rem & 15) >> 2) + ((rem >> 4) << 2);
        const int h  = n0 >> 6;
#pragma unroll
        for (int s = 0; s < 4; ++s) {
            const int d = 16 * s + c;
            const float bb = bias[n0 + d];
            ushort4 o;
            o.x = f2bf(acc[s][0] + bb);
            o.y = f2bf(acc[s][1] + bb);
            o.z = f2bf(acc[s][2] + bb);
            o.w = f2bf(acc[s][3] + bb);
            *(ushort4*)(vt + ((size_t)(b_ * NHEADS + h) * HD + d) * SEQ + pos) = o;
        }
    }
}

// ---------------------------------------------------------------------------
// K2: fused flash attention (R11/R13 structure: SPLIT-KV, 8 waves/block,
// K/V LDS-staged XOR-swizzled double-buffered).  O written as bf16 hi+lo
// (for the MFMA out-projection).
// ---------------------------------------------------------------------------
__global__ __launch_bounds__(512, 4) void mha_fused(
    const short* __restrict__ qb, const short* __restrict__ kb,
    const short* __restrict__ vt,
    float* __restrict__ wts,
    unsigned short* __restrict__ attn_h, unsigned short* __restrict__ attn_l)
{
    __shared__ short KsA[2][4096];
    __shared__ short VsA[2][4096];
    __shared__ short KsB[2][4096];
    __shared__ short VsB[2][4096];
    __shared__ float lx[512];

    const int bh = blockIdx.y;
    const int q0 = blockIdx.x * 64;
    const int t = threadIdx.x;
    const int w = t >> 6;          // 0..7
    const int grp = w >> 2;        // 0: kv [0,1024)  1: kv [1024,2048)
    const int wq = w & 3;          // q sub-tile
    const int lane = t & 63;
    const int g = lane >> 4;
    const int c = lane & 15;
    const int q = q0 + wq * 16 + c;

    const short* qrow = qb + ((size_t)bh * SEQ + q) * HD + 8 * g;
    const bf16x8 qf0 = *(const bf16x8*)(qrow);
    const bf16x8 qf1 = *(const bf16x8*)(qrow + 32);

    const int rs = t >> 3, bls = t & 7;
    const int dss = rs * 64 + ((bls ^ (rs & 7)) << 3);
    const short* kgb = kb + (size_t)bh * SEQ * HD;
    const short* vgb = vt + (size_t)bh * HD * SEQ;

    int koff[4][2];
#pragma unroll
    for (int s = 0; s < 4; ++s) {
        const int rr = c + 16 * s;
        koff[s][0] = rr * 64 + (((g    ) ^ (rr & 7)) << 3);
        koff[s][1] = rr * 64 + (((g + 4) ^ (rr & 7)) << 3);
    }
    int voff2[4][2];
#pragma unroll
    for (int s = 0; s < 4; ++s) {
        const int rv = 16 * s + c;
        voff2[s][0] = rv * 64 + (((g    ) ^ (rv & 7)) << 3);
        voff2[s][1] = rv * 64 + (((g + 4) ^ (rv & 7)) << 3);
    }

    const float scale2 = 0.125f * 1.44269504f;   // 1/sqrt(64) * log2(e)

    // ---- pass 1: row sums of exp2(s*scale2), each group over its half ---
    float l = 0.f;

    auto sum_tile = [&](const short* Kb) {
        f32x4 a0 = {0.f,0.f,0.f,0.f}, a1 = {0.f,0.f,0.f,0.f};
        f32x4 a2 = {0.f,0.f,0.f,0.f}, a3 = {0.f,0.f,0.f,0.f};
        __builtin_amdgcn_s_setprio(1);
        a0 = __builtin_amdgcn_mfma_f32_16x16x32_bf16(*(const bf16x8*)(Kb + koff[0][0]), qf0, a0, 0, 0, 0);
        a0 = __builtin_amdgcn_mfma_f32_16x16x32_bf16(*(const bf16x8*)(Kb + koff[0][1]), qf1, a0, 0, 0, 0);
        a1 = __builtin_amdgcn_mfma_f32_16x16x32_bf16(*(const bf16x8*)(Kb + koff[1][0]), qf0, a1, 0, 0, 0);
        a1 = __builtin_amdgcn_mfma_f32_16x16x32_bf16(*(const bf16x8*)(Kb + koff[1][1]), qf1, a1, 0, 0, 0);
        a2 = __builtin_amdgcn_mfma_f32_16x16x32_bf16(*(const bf16x8*)(Kb + koff[2][0]), qf0, a2, 0, 0, 0);
        a2 = __builtin_amdgcn_mfma_f32_16x16x32_bf16(*(const bf16x8*)(Kb + koff[2][1]), qf1, a2, 0, 0, 0);
        a3 = __builtin_amdgcn_mfma_f32_16x16x32_bf16(*(const bf16x8*)(Kb + koff[3][0]), qf0, a3, 0, 0, 0);
        a3 = __builtin_amdgcn_mfma_f32_16x16x32_bf16(*(const bf16x8*)(Kb + koff[3][1]), qf1, a3, 0, 0, 0);
        __builtin_amdgcn_s_setprio(0);
        float ts = 0.f;
#pragma unroll
        for (int r = 0; r < 4; ++r) {
            ts += __builtin_amdgcn_exp2f(a0[r] * scale2);
            ts += __builtin_amdgcn_exp2f(a1[r] * scale2);
            ts += __builtin_amdgcn_exp2f(a2[r] * scale2);
            ts += __builtin_amdgcn_exp2f(a3[r] * scale2);
        }
        ts += __shfl_xor(ts, 16);
        ts += __shfl_xor(ts, 32);
        l += ts;
    };

    {
        uint4 kA = *(const uint4*)(kgb + (size_t)0  * 64 * HD + (size_t)t * 8);
        uint4 kB = *(const uint4*)(kgb + (size_t)16 * 64 * HD + (size_t)t * 8);
        *(uint4*)(&KsA[0][dss]) = kA;
        *(uint4*)(&KsB[0][dss]) = kB;
    }
    __syncthreads();
    int cur = 0;
    for (int ktl = 0; ktl < 16; ++ktl) {
        uint4 nA, nB;
        if (ktl < 15) {
            nA = *(const uint4*)(kgb + (size_t)(ktl + 1)  * 64 * HD + (size_t)t * 8);
            nB = *(const uint4*)(kgb + (size_t)(ktl + 17) * 64 * HD + (size_t)t * 8);
        }
        sum_tile(grp ? &KsB[cur][0] : &KsA[cur][0]);
        if (ktl < 15) {
            *(uint4*)(&KsA[cur ^ 1][dss]) = nA;
            *(uint4*)(&KsB[cur ^ 1][dss]) = nB;
        }
        __syncthreads();
        cur ^= 1;
    }

    lx[t] = l;
    __syncthreads();
    l = lx[t] + lx[t ^ 256];
    const float c0 = -__builtin_amdgcn_logf(l);   // p = exp2(s*scale2 + c0)
    __syncthreads();

    // ---- pass 2: weights + PV over this group's half --------------------
    f32x4 o0 = {0.f,0.f,0.f,0.f}, o1 = {0.f,0.f,0.f,0.f};
    f32x4 o2 = {0.f,0.f,0.f,0.f}, o3 = {0.f,0.f,0.f,0.f};
    float* __restrict__ wrow = wts + ((size_t)bh * SEQ + q) * SEQ;

    auto pv_tile = [&](const short* Kb, const short* Vb, int kv0) {
        f32x4 a0 = {0.f,0.f,0.f,0.f}, a1 = {0.f,0.f,0.f,0.f};
        f32x4 a2 = {0.f,0.f,0.f,0.f}, a3 = {0.f,0.f,0.f,0.f};
        __builtin_amdgcn_s_setprio(1);
        a0 = __builtin_amdgcn_mfma_f32_16x16x32_bf16(*(const bf16x8*)(Kb + koff[0][0]), qf0, a0, 0, 0, 0);
        a0 = __builtin_amdgcn_mfma_f32_16x16x32_bf16(*(const bf16x8*)(Kb + koff[0][1]), qf1, a0, 0, 0, 0);
        a1 = __builtin_amdgcn_mfma_f32_16x16x32_bf16(*(const bf16x8*)(Kb + koff[1][0]), qf0, a1, 0, 0, 0);
        a1 = __builtin_amdgcn_mfma_f32_16x16x32_bf16(*(const bf16x8*)(Kb + koff[1][1]), qf1, a1, 0, 0, 0);
        a2 = __builtin_amdgcn_mfma_f32_16x16x32_bf16(*(const bf16x8*)(Kb + koff[2][0]), qf0, a2, 0, 0, 0);
        a2 = __builtin_amdgcn_mfma_f32_16x16x32_bf16(*(const bf16x8*)(Kb + koff[2][1]), qf1, a2, 0, 0, 0);
        a3 = __builtin_amdgcn_mfma_f32_16x16x32_bf16(*(const bf16x8*)(Kb + koff[3][0]), qf0, a3, 0, 0, 0);
        a3 = __builtin_amdgcn_mfma_f32_16x16x32_bf16(*(const bf16x8*)(Kb + koff[3][1]), qf1, a3, 0, 0, 0);
        __builtin_amdgcn_s_setprio(0);

        float pn[4][4];
#pragma unroll
        for (int r = 0; r < 4; ++r) {
            pn[0][r] = __builtin_amdgcn_exp2f(fmaf(a0[r], scale2, c0));
            pn[1][r] = __builtin_amdgcn_exp2f(fmaf(a1[r], scale2, c0));
            pn[2][r] = __builtin_amdgcn_exp2f(fmaf(a2[r], scale2, c0));
            pn[3][r] = __builtin_amdgcn_exp2f(fmaf(a3[r], scale2, c0));
        }
        union { bf16x8 v; unsigned u[4]; } pf0, pf1;
        pf0.u[0] = (__float_as_uint(pn[0][0]) >> 16) | (__float_as_uint(pn[0][1]) & 0xffff0000u);
        pf0.u[1] = (__float_as_uint(pn[0][2]) >> 16) | (__float_as_uint(pn[0][3]) & 0xffff0000u);
        pf0.u[2] = (__float_as_uint(pn[1][0]) >> 16) | (__float_as_uint(pn[1][1]) & 0xffff0000u);
        pf0.u[3] = (__float_as_uint(pn[1][2]) >> 16) | (__float_as_uint(pn[1][3]) & 0xffff0000u);
        pf1.u[0] = (__float_as_uint(pn[2][0]) >> 16) | (__float_as_uint(pn[2][1]) & 0xffff0000u);
        pf1.u[1] = (__float_as_uint(pn[2][2]) >> 16) | (__float_as_uint(pn[2][3]) & 0xffff0000u);
        pf1.u[2] = (__float_as_uint(pn[3][0]) >> 16) | (__float_as_uint(pn[3][1]) & 0xffff0000u);
        pf1.u[3] = (__float_as_uint(pn[3][2]) >> 16) | (__float_as_uint(pn[3][3]) & 0xffff0000u);

        __builtin_amdgcn_s_setprio(1);
#pragma unroll
        for (int sub = 0; sub < 4; ++sub) {
            const bf16x8 vf0 = *(const bf16x8*)(Vb + voff2[sub][0]);
            const bf16x8 vf1 = *(const bf16x8*)(Vb + voff2[sub][1]);
            f32x4& o = (sub == 0) ? o0 : (sub == 1) ? o1 : (sub == 2) ? o2 : o3;
            o = __builtin_amdgcn_mfma_f32_16x16x32_bf16(pf0.v, vf0, o, 0, 0, 0);
            o = __builtin_amdgcn_mfma_f32_16x16x32_bf16(pf1.v, vf1, o, 0, 0, 0);
        }
        __builtin_amdgcn_s_setprio(0);
#pragma unroll
        for (int s = 0; s < 4; ++s) {
            float4 st;
            st.x = pn[s][0]; st.y = pn[s][1]; st.z = pn[s][2]; st.w = pn[s][3];
            *(float4*)(wrow + kv0 + 16 * s + 4 * g) = st;
        }
    };

    {
        uint4 kA = *(const uint4*)(kgb + (size_t)0  * 64 * HD + (size_t)t * 8);
        uint4 kB = *(const uint4*)(kgb + (size_t)16 * 64 * HD + (size_t)t * 8);
        uint4 vA = *(const uint4*)(vgb + (size_t)rs * SEQ + 0    + bls * 8);
        uint4 vB = *(const uint4*)(vgb + (size_t)rs * SEQ + 1024 + bls * 8);
        *(uint4*)(&KsA[0][dss]) = kA;  *(uint4*)(&KsB[0][dss]) = kB;
        *(uint4*)(&VsA[0][dss]) = vA;  *(uint4*)(&VsB[0][dss]) = vB;
    }
    __syncthreads();
    cur = 0;
    for (int ktl = 0; ktl < 16; ++ktl) {
        uint4 nKA, nKB, nVA, nVB;
        if (ktl < 15) {
            nKA = *(const uint4*)(kgb + (size_t)(ktl + 1)  * 64 * HD + (size_t)t * 8);
            nKB = *(const uint4*)(kgb + (size_t)(ktl + 17) * 64 * HD + (size_t)t * 8);
            nVA = *(const uint4*)(vgb + (size_t)rs * SEQ + (ktl + 1)  * 64 + bls * 8);
            nVB = *(const uint4*)(vgb + (size_t)rs * SEQ + (ktl + 17) * 64 + bls * 8);
        }
        if (grp == 0) pv_tile(&KsA[cur][0], &VsA[cur][0], ktl * 64);
        else          pv_tile(&KsB[cur][0], &VsB[cur][0], 1024 + ktl * 64);
        if (ktl < 15) {
            *(uint4*)(&KsA[cur ^ 1][dss]) = nKA;  *(uint4*)(&KsB[cur ^ 1][dss]) = nKB;
            *(uint4*)(&VsA[cur ^ 1][dss]) = nVA;  *(uint4*)(&VsB[cur ^ 1][dss]) = nVB;
        }
        __syncthreads();
        cur ^= 1;
    }

    // ---- merge partial O across groups, write bf16 hi/lo attn -----------
    float* sc = (float*)&KsA[0][0];   // 16 KB scratch
    if (w >= 4) {
        const int base = ((w - 4) * 64 + lane) * 16;
#pragma unroll
        for (int r = 0; r < 4; ++r) {
            sc[base + 0  + r] = o0[r];
            sc[base + 4  + r] = o1[r];
            sc[base + 8  + r] = o2[r];
            sc[base + 12 + r] = o3[r];
        }
    }
    __syncthreads();
    if (w < 4) {
        const int base = (w * 64 + lane) * 16;
        const size_t abase = ((size_t)bh * SEQ + q0 + 16 * w) * HD;
#pragma unroll
        for (int r = 0; r < 4; ++r) {
            const float v0 = o0[r] + sc[base + 0  + r];
            const float v1 = o1[r] + sc[base + 4  + r];
            const float v2 = o2[r] + sc[base + 8  + r];
            const float v3 = o3[r] + sc[base + 12 + r];
            const size_t ro = abase + (size_t)(4 * g + r) * HD + c;
            unsigned short h16;
            h16 = f2bf(v0); attn_h[ro +  0] = h16; attn_l[ro +  0] = f2bf(v0 - bf2f(h16));
            h16 = f2bf(v1); attn_h[ro + 16] = h16; attn_l[ro + 16] = f2bf(v1 - bf2f(h16));
            h16 = f2bf(v2); attn_h[ro + 32] = h16; attn_l[ro + 32] = f2bf(v2 - bf2f(h16));
            h16 = f2bf(v3); attn_h[ro + 48] = h16; attn_l[ro + 48] = f2bf(v3 - bf2f(h16));
        }
    }
}

// ---------------------------------------------------------------------------
// K3: out = concat(attn) @ Wo + bo on MFMA, ALL OPERANDS LDS-STAGED
// (XOR-swizzled, same verified geometry as the fused kernel's K staging).
// Block 64m x 64n, 256 thr, 4 waves (wave w: m-rows 16w..+15, all 64 n).
// K-loop over 8 heads (64 k each); 3-term split-bf16.  grid (64, 8).
// ---------------------------------------------------------------------------
__global__ __launch_bounds__(256) void mha_oproj_mfma(
    const unsigned short* __restrict__ ath, const unsigned short* __restrict__ atl,
    const unsigned short* __restrict__ wto,
    const float* __restrict__ bo, float* __restrict__ out)
{
    __shared__ short Ah[4096], Al[4096], Bh[4096], Bl[4096];   // [64 row][64 k]

    const int m0 = blockIdx.x * 64;
    const int n0 = blockIdx.y * 64;
    const int t = threadIdx.x;
    const int w = t >> 6;
    const int lane = t & 63;
    const int g = lane >> 4;
    const int c = lane & 15;

    // staging: chunk0 = t (row t>>3, bl t&7), chunk1 = t+256 (row +32)
    const int rs = t >> 3, bls = t & 7;
    const int ds0 = rs * 64 + ((bls ^ (rs & 7)) << 3);
    const int rs1 = rs + 32;
    const int ds1 = rs1 * 64 + ((bls ^ (rs1 & 7)) << 3);

    // A global source rows: m = m0 + r  (blocks never straddle batch bound)
    const int b_ = m0 >> 11;
    const size_t abase0 = ((size_t)(b_ * NHEADS) * SEQ + (m0 & 2047)) * HD;
    // per-k-chunk (head h) A addr: abase0 + h*SEQ*HD + r*HD + bls*8
    const size_t aoffr0 = (size_t)rs  * HD + bls * 8;
    const size_t aoffr1 = (size_t)rs1 * HD + bls * 8;
    // B source: wto[z][n0+r][h*64 + bls*8]
    const short* wh_g = (const short*)wto + (size_t)(n0 + rs)  * EMBED + bls * 8;
    const short* wh_g1 = (const short*)wto + (size_t)(n0 + rs1) * EMBED + bls * 8;
    const short* wl_g  = wh_g  + (size_t)EMBED * EMBED;
    const short* wl_g1 = wh_g1 + (size_t)EMBED * EMBED;

    // fragment LDS offsets: A row = 16w + c ; B row = 16s + c
    int aoff[2];
    {
        const int rr = 16 * w + c;
        aoff[0] = rr * 64 + (((g    ) ^ (rr & 7)) << 3);
        aoff[1] = rr * 64 + (((g + 4) ^ (rr & 7)) << 3);
    }
    int boff[4][2];
#pragma unroll
    for (int s = 0; s < 4; ++s) {
        const int rr = 16 * s + c;
        boff[s][0] = rr * 64 + (((g    ) ^ (rr & 7)) << 3);
        boff[s][1] = rr * 64 + (((g + 4) ^ (rr & 7)) << 3);
    }

    f32x4 acc[4];
#pragma unroll
    for (int s = 0; s < 4; ++s) acc[s] = (f32x4){0.f, 0.f, 0.f, 0.f};

    // prologue: stage head 0
    {
        const short* ag = (const short*)ath + abase0;
        const short* lg = (const short*)atl + abase0;
        *(uint4*)(&Ah[ds0]) = *(const uint4*)(ag + aoffr0);
        *(uint4*)(&Ah[ds1]) = *(const uint4*)(ag + aoffr1);
        *(uint4*)(&Al[ds0]) = *(const uint4*)(lg + aoffr0);
        *(uint4*)(&Al[ds1]) = *(const uint4*)(lg + aoffr1);
        *(uint4*)(&Bh[ds0]) = *(const uint4*)(wh_g);
        *(uint4*)(&Bh[ds1]) = *(const uint4*)(wh_g1);
        *(uint4*)(&Bl[ds0]) = *(const uint4*)(wl_g);
        *(uint4*)(&Bl[ds1]) = *(const uint4*)(wl_g1);
    }
    __syncthreads();

    for (int h = 0; h < 8; ++h) {
        uint4 nA0, nA1, nL0, nL1, nB0, nB1, nC0, nC1;
        if (h < 7) {
            const short* ag = (const short*)ath + abase0 + (size_t)(h + 1) * SEQ * HD;
            const short* lg = (const short*)atl + abase0 + (size_t)(h + 1) * SEQ * HD;
            nA0 = *(const uint4*)(ag + aoffr0);
            nA1 = *(const uint4*)(ag + aoffr1);
            nL0 = *(const uint4*)(lg + aoffr0);
            nL1 = *(const uint4*)(lg + aoffr1);
            nB0 = *(const uint4*)(wh_g  + (h + 1) * 64);
            nB1 = *(const uint4*)(wh_g1 + (h + 1) * 64);
            nC0 = *(const uint4*)(wl_g  + (h + 1) * 64);
            nC1 = *(const uint4*)(wl_g1 + (h + 1) * 64);
        }

        const bf16x8 ah0 = *(const bf16x8*)(Ah + aoff[0]);
        const bf16x8 ah1 = *(const bf16x8*)(Ah + aoff[1]);
        const bf16x8 al0 = *(const bf16x8*)(Al + aoff[0]);
        const bf16x8 al1 = *(const bf16x8*)(Al + aoff[1]);
        __builtin_amdgcn_s_setprio(1);
#pragma unroll
        for (int s = 0; s < 4; ++s) {
            const bf16x8 bh0 = *(const bf16x8*)(Bh + boff[s][0]);
            const bf16x8 bh1 = *(const bf16x8*)(Bh + boff[s][1]);
            const bf16x8 bl0 = *(const bf16x8*)(Bl + boff[s][0]);
            const bf16x8 bl1 = *(const bf16x8*)(Bl + boff[s][1]);
            acc[s] = __builtin_amdgcn_mfma_f32_16x16x32_bf16(ah0, bh0, acc[s], 0, 0, 0);
            acc[s] = __builtin_amdgcn_mfma_f32_16x16x32_bf16(ah1, bh1, acc[s], 0, 0, 0);
            acc[s] = __builtin_amdgcn_mfma_f32_16x16x32_bf16(al0, bh0, acc[s], 0, 0, 0);
            acc[s] = __builtin_amdgcn_mfma_f32_16x16x32_bf16(al1, bh1, acc[s], 0, 0, 0);
            acc[s] = __builtin_amdgcn_mfma_f32_16x16x32_bf16(ah0, bl0, acc[s], 0, 0, 0);
            acc[s] = __builtin_amdgcn_mfma_f32_16x16x32_bf16(ah1, bl1, acc[s], 0, 0, 0);
        }
        __builtin_amdgcn_s_setprio(0);

        __syncthreads();
        if (h < 7) {
            *(uint4*)(&Ah[ds0]) = nA0;  *(uint4*)(&Ah[ds1]) = nA1;
            *(uint4*)(&Al[ds0]) = nL0;  *(uint4*)(&Al[ds1]) = nL1;
            *(uint4*)(&Bh[ds0]) = nB0;  *(uint4*)(&Bh[ds1]) = nB1;
            *(uint4*)(&Bl[ds0]) = nC0;  *(uint4*)(&Bl[ds1]) = nC1;
        }
        __syncthreads();
    }

    // epilogue: C/D row m = 16w + 4g + r, col n = n0 + 16s + c
#pragma unroll
    for (int s = 0; s < 4; ++s) {
        const int n = n0 + 16 * s + c;
        const float bb = bo[n];
#pragma unroll
        for (int r = 0; r < 4; ++r) {
            const int m = m0 + 16 * w + 4 * g + r;
            out[(size_t)m * EMBED + n] = acc[s][r] + bb;
        }
    }
}

// ---------------------------------------------------------------------------
extern "C" void kernel_launch(void* const* d_in, const int* in_sizes, int n_in,
                              void* d_out, int out_size, void* d_ws, size_t ws_size,
                              hipStream_t stream)
{
    const float* x  = (const float*)d_in[0];
    const float* Wq = (const float*)d_in[1];
    const float* bq = (const float*)d_in[2];
    const float* Wk = (const float*)d_in[3];
    const float* bk = (const float*)d_in[4];
    const float* Wv = (const float*)d_in[5];
    const float* bv = (const float*)d_in[6];
    const float* Wo = (const float*)d_in[7];
    const float* bo = (const float*)d_in[8];

    float* out = (float*)d_out;                      // [2,2048,512]
    float* wts = out + (size_t)2 * SEQ * EMBED;      // [2,8,2048,2048]

    unsigned short* qbw = (unsigned short*)d_ws;             // bf16 [16][2048][64]
    unsigned short* kbw = qbw + (size_t)NBH * SEQ * HD;      // bf16 [16][2048][64]
    unsigned short* vtw = kbw + (size_t)NBH * SEQ * HD;      // bf16 [16][64][2048] (kv-permuted)
    unsigned short* ath = vtw + (size_t)NBH * SEQ * HD;      // bf16 [16][2048][64]
    unsigned short* atl = ath + (size_t)NBH * SEQ * HD;      // bf16 [16][2048][64]
    unsigned short* xh  = atl + (size_t)NBH * SEQ * HD;      // bf16 [4096][512]
    unsigned short* xl  = xh + (size_t)MROWS * EMBED;        // bf16 [4096][512]
    unsigned short* wtw = xl + (size_t)MROWS * EMBED;        // bf16 [3][512][512]
    unsigned short* wto = wtw + (size_t)3 * EMBED * EMBED;   // bf16 [2][512][512]

    cvt_x<<<dim3(MROWS * EMBED / 4 / 256), 256, 0, stream>>>(x, xh, xl);
    cvt_w<<<dim3(8, 8, 5), 256, 0, stream>>>(Wq, Wk, Wv, Wo, wtw, wto);
    mha_qkv_mfma<<<dim3(64, 24), 256, 0, stream>>>(xh, xl, wtw, bq, bk, bv,
                                                   qbw, kbw, vtw);
    mha_fused  <<<dim3(32, NBH), 512, 0, stream>>>((const short*)qbw, (const short*)kbw,
                                                   (const short*)vtw, wts, ath, atl);
    mha_oproj_mfma<<<dim3(64, 8), 256, 0, stream>>>(ath, atl, wto, bo, out);
}

// Round 15
// 116.418 us; speedup vs baseline: 2.7055x; 1.4164x over previous
//
#include <hip/hip_runtime.h>
#include <cstddef>

#define EMBED 512
#define NHEADS 8
#define HD 64
#define SEQ 2048
#define NBH 16      // B * NHEADS
#define MROWS 4096  // B * SEQ

typedef __attribute__((ext_vector_type(8))) short bf16x8;
typedef __attribute__((ext_vector_type(4))) float f32x4;

__device__ __forceinline__ unsigned short f2bf(float x) {
    union { float f; unsigned u; } v; v.f = x;
    unsigned r = v.u + 0x7fffu + ((v.u >> 16) & 1u);
    return (unsigned short)(r >> 16);
}
__device__ __forceinline__ float bf2f(unsigned short u) {
    union { unsigned u; float f; } v; v.u = ((unsigned)u) << 16;
    return v.f;
}

// ---------------------------------------------------------------------------
// K0a: split x (fp32) into x_hi + x_lo (bf16 each).
// ---------------------------------------------------------------------------
__global__ __launch_bounds__(256) void cvt_x(
    const float* __restrict__ x, unsigned short* __restrict__ xh,
    unsigned short* __restrict__ xl)
{
    const int i = blockIdx.x * 256 + threadIdx.x;      // float4 index
    float4 v = ((const float4*)x)[i];
    ushort4 h, lo;
    h.x = f2bf(v.x); lo.x = f2bf(v.x - bf2f(h.x));
    h.y = f2bf(v.y); lo.y = f2bf(v.y - bf2f(h.y));
    h.z = f2bf(v.z); lo.z = f2bf(v.z - bf2f(h.z));
    h.w = f2bf(v.w); lo.w = f2bf(v.w - bf2f(h.w));
    ((ushort4*)xh)[i] = h;
    ((ushort4*)xl)[i] = lo;
}

// ---------------------------------------------------------------------------
// K0b: weight transposes to bf16.  z=0..2: Wq/Wk/Wv -> wt[z][n][k] (hi only).
// z=3: Wo hi -> wto[0];  z=4: Wo lo -> wto[1].
// ---------------------------------------------------------------------------
__global__ __launch_bounds__(256) void cvt_w(
    const float* __restrict__ Wq, const float* __restrict__ Wk,
    const float* __restrict__ Wv, const float* __restrict__ Wo,
    unsigned short* __restrict__ wt, unsigned short* __restrict__ wto)
{
    __shared__ float Ws[64][65];
    const int z = blockIdx.z;
    const float* __restrict__ W = (z == 0) ? Wq : (z == 1) ? Wk : (z == 2) ? Wv : Wo;
    const int k0 = blockIdx.x * 64, n0 = blockIdx.y * 64;
    const int t = threadIdx.x;
#pragma unroll
    for (int l = 0; l < 4; ++l) {
        const int idx = t + 256 * l;
        const int r = idx >> 4, c4 = (idx & 15) * 4;
        float4 w = *(const float4*)(W + (size_t)(k0 + r) * EMBED + n0 + c4);
        Ws[r][c4 + 0] = w.x; Ws[r][c4 + 1] = w.y;
        Ws[r][c4 + 2] = w.z; Ws[r][c4 + 3] = w.w;
    }
    __syncthreads();
    unsigned short* __restrict__ dst =
        (z < 3) ? (wt + (size_t)z * EMBED * EMBED)
                : (wto + (size_t)(z - 3) * EMBED * EMBED);
#pragma unroll
    for (int l = 0; l < 4; ++l) {
        const int idx = t + 256 * l;
        const int rn = idx >> 4, k4 = (idx & 15) * 4;
        ushort4 o;
        if (z == 4) {
            float v0 = Ws[k4 + 0][rn], v1 = Ws[k4 + 1][rn];
            float v2 = Ws[k4 + 2][rn], v3 = Ws[k4 + 3][rn];
            o.x = f2bf(v0 - bf2f(f2bf(v0)));
            o.y = f2bf(v1 - bf2f(f2bf(v1)));
            o.z = f2bf(v2 - bf2f(f2bf(v2)));
            o.w = f2bf(v3 - bf2f(f2bf(v3)));
        } else {
            o.x = f2bf(Ws[k4 + 0][rn]);
            o.y = f2bf(Ws[k4 + 1][rn]);
            o.z = f2bf(Ws[k4 + 2][rn]);
            o.w = f2bf(Ws[k4 + 3][rn]);
        }
        *(ushort4*)(dst + (size_t)(n0 + rn) * EMBED + k0 + k4) = o;
    }
}

// ---------------------------------------------------------------------------
// K1: QKV projection on MFMA, ALL OPERANDS LDS-STAGED (clone of the R14-
// verified oproj skeleton).  Block 64m x 64n, 4 waves; K-loop 8 chunks of 64.
// out = (x_hi + x_lo) @ W_z + b_z, bf16 out; v -> vt with kv permutation.
// grid (64, 24): by -> z = by/8, n0 = (by%8)*64.
// ---------------------------------------------------------------------------
__global__ __launch_bounds__(256) void mha_qkv_mfma(
    const unsigned short* __restrict__ xh, const unsigned short* __restrict__ xl,
    const unsigned short* __restrict__ wt,
    const float* __restrict__ bq, const float* __restrict__ bk,
    const float* __restrict__ bv,
    unsigned short* __restrict__ qo, unsigned short* __restrict__ ko,
    unsigned short* __restrict__ vt)
{
    __shared__ short Ah[4096], Al[4096], Bh[4096];   // [64 row][64 k]

    const int m0 = blockIdx.x * 64;
    const int z  = blockIdx.y >> 3;
    const int n0 = (blockIdx.y & 7) * 64;
    const float* __restrict__ bias = (z == 0) ? bq : (z == 1) ? bk : bv;

    const int t = threadIdx.x;
    const int w = t >> 6;
    const int lane = t & 63;
    const int g = lane >> 4;
    const int c = lane & 15;

    // staging geometry (verified): chunk0 row rs, chunk1 row rs+32
    const int rs = t >> 3, bls = t & 7;
    const int ds0 = rs * 64 + ((bls ^ (rs & 7)) << 3);
    const int rs1 = rs + 32;
    const int ds1 = rs1 * 64 + ((bls ^ (rs1 & 7)) << 3);

    const short* xh_g0 = (const short*)xh + (size_t)(m0 + rs)  * EMBED + bls * 8;
    const short* xh_g1 = (const short*)xh + (size_t)(m0 + rs1) * EMBED + bls * 8;
    const short* xl_g0 = (const short*)xl + (size_t)(m0 + rs)  * EMBED + bls * 8;
    const short* xl_g1 = (const short*)xl + (size_t)(m0 + rs1) * EMBED + bls * 8;
    const short* w_g0  = (const short*)wt + (size_t)z * EMBED * EMBED
                       + (size_t)(n0 + rs)  * EMBED + bls * 8;
    const short* w_g1  = (const short*)wt + (size_t)z * EMBED * EMBED
                       + (size_t)(n0 + rs1) * EMBED + bls * 8;

    // fragment LDS offsets: A row = 16w + c ; B row = 16s + c
    int aoff[2];
    {
        const int rr = 16 * w + c;
        aoff[0] = rr * 64 + (((g    ) ^ (rr & 7)) << 3);
        aoff[1] = rr * 64 + (((g + 4) ^ (rr & 7)) << 3);
    }
    int boff[4][2];
#pragma unroll
    for (int s = 0; s < 4; ++s) {
        const int rr = 16 * s + c;
        boff[s][0] = rr * 64 + (((g    ) ^ (rr & 7)) << 3);
        boff[s][1] = rr * 64 + (((g + 4) ^ (rr & 7)) << 3);
    }

    f32x4 acc[4];
#pragma unroll
    for (int s = 0; s < 4; ++s) acc[s] = (f32x4){0.f, 0.f, 0.f, 0.f};

    // prologue: stage k-chunk 0
    {
        *(uint4*)(&Ah[ds0]) = *(const uint4*)(xh_g0);
        *(uint4*)(&Ah[ds1]) = *(const uint4*)(xh_g1);
        *(uint4*)(&Al[ds0]) = *(const uint4*)(xl_g0);
        *(uint4*)(&Al[ds1]) = *(const uint4*)(xl_g1);
        *(uint4*)(&Bh[ds0]) = *(const uint4*)(w_g0);
        *(uint4*)(&Bh[ds1]) = *(const uint4*)(w_g1);
    }
    __syncthreads();

    for (int kc = 0; kc < 8; ++kc) {
        uint4 nA0, nA1, nL0, nL1, nB0, nB1;
        if (kc < 7) {
            const int ko = (kc + 1) * 64;
            nA0 = *(const uint4*)(xh_g0 + ko);
            nA1 = *(const uint4*)(xh_g1 + ko);
            nL0 = *(const uint4*)(xl_g0 + ko);
            nL1 = *(const uint4*)(xl_g1 + ko);
            nB0 = *(const uint4*)(w_g0 + ko);
            nB1 = *(const uint4*)(w_g1 + ko);
        }

        const bf16x8 ah0 = *(const bf16x8*)(Ah + aoff[0]);
        const bf16x8 ah1 = *(const bf16x8*)(Ah + aoff[1]);
        const bf16x8 al0 = *(const bf16x8*)(Al + aoff[0]);
        const bf16x8 al1 = *(const bf16x8*)(Al + aoff[1]);
        __builtin_amdgcn_s_setprio(1);
#pragma unroll
        for (int s = 0; s < 4; ++s) {
            const bf16x8 bh0 = *(const bf16x8*)(Bh + boff[s][0]);
            const bf16x8 bh1 = *(const bf16x8*)(Bh + boff[s][1]);
            acc[s] = __builtin_amdgcn_mfma_f32_16x16x32_bf16(ah0, bh0, acc[s], 0, 0, 0);
            acc[s] = __builtin_amdgcn_mfma_f32_16x16x32_bf16(ah1, bh1, acc[s], 0, 0, 0);
            acc[s] = __builtin_amdgcn_mfma_f32_16x16x32_bf16(al0, bh0, acc[s], 0, 0, 0);
            acc[s] = __builtin_amdgcn_mfma_f32_16x16x32_bf16(al1, bh1, acc[s], 0, 0, 0);
        }
        __builtin_amdgcn_s_setprio(0);

        __syncthreads();
        if (kc < 7) {
            *(uint4*)(&Ah[ds0]) = nA0;  *(uint4*)(&Ah[ds1]) = nA1;
            *(uint4*)(&Al[ds0]) = nL0;  *(uint4*)(&Al[ds1]) = nL1;
            *(uint4*)(&Bh[ds0]) = nB0;  *(uint4*)(&Bh[ds1]) = nB1;
        }
        __syncthreads();
    }

    if (z < 2) {
        unsigned short* __restrict__ out = (z == 0) ? qo : ko;
#pragma unroll
        for (int s = 0; s < 4; ++s) {
            const int n = n0 + 16 * s + c;
            const int h = n >> 6, d = n & 63;
            const float bb = bias[n];
#pragma unroll
            for (int r = 0; r < 4; ++r) {
                const int m  = m0 + 16 * w + 4 * g + r;
                const int b_ = m >> 11, sm = m & 2047;
                out[((size_t)(b_ * NHEADS + h) * SEQ + sm) * HD + d] =
                    f2bf(acc[s][r] + bb);
            }
        }
    } else {
        const int m  = m0 + 16 * w + 4 * g;     // base kv of the 4-row chunk
        const int b_ = m >> 11, sm = m & 2047;
        const int a  = sm >> 5, rem = sm & 31;
        const int pos = 32 * a + 8 * ((rem & 15) >> 2) + ((rem >> 4) << 2);
        const int h  = n0 >> 6;
#pragma unroll
        for (int s = 0; s < 4; ++s) {
            const int d = 16 * s + c;
            const float bb = bias[n0 + d];
            ushort4 o;
            o.x = f2bf(acc[s][0] + bb);
            o.y = f2bf(acc[s][1] + bb);
            o.z = f2bf(acc[s][2] + bb);
            o.w = f2bf(acc[s][3] + bb);
            *(ushort4*)(vt + ((size_t)(b_ * NHEADS + h) * HD + d) * SEQ + pos) = o;
        }
    }
}

// ---------------------------------------------------------------------------
// K2: fused flash attention (R11/R13 structure: SPLIT-KV, 8 waves/block,
// K/V LDS-staged XOR-swizzled double-buffered).  O written as bf16 hi+lo
// (for the MFMA out-projection).
// ---------------------------------------------------------------------------
__global__ __launch_bounds__(512, 4) void mha_fused(
    const short* __restrict__ qb, const short* __restrict__ kb,
    const short* __restrict__ vt,
    float* __restrict__ wts,
    unsigned short* __restrict__ attn_h, unsigned short* __restrict__ attn_l)
{
    __shared__ short KsA[2][4096];
    __shared__ short VsA[2][4096];
    __shared__ short KsB[2][4096];
    __shared__ short VsB[2][4096];
    __shared__ float lx[512];

    const int bh = blockIdx.y;
    const int q0 = blockIdx.x * 64;
    const int t = threadIdx.x;
    const int w = t >> 6;          // 0..7
    const int grp = w >> 2;        // 0: kv [0,1024)  1: kv [1024,2048)
    const int wq = w & 3;          // q sub-tile
    const int lane = t & 63;
    const int g = lane >> 4;
    const int c = lane & 15;
    const int q = q0 + wq * 16 + c;

    const short* qrow = qb + ((size_t)bh * SEQ + q) * HD + 8 * g;
    const bf16x8 qf0 = *(const bf16x8*)(qrow);
    const bf16x8 qf1 = *(const bf16x8*)(qrow + 32);

    const int rs = t >> 3, bls = t & 7;
    const int dss = rs * 64 + ((bls ^ (rs & 7)) << 3);
    const short* kgb = kb + (size_t)bh * SEQ * HD;
    const short* vgb = vt + (size_t)bh * HD * SEQ;

    int koff[4][2];
#pragma unroll
    for (int s = 0; s < 4; ++s) {
        const int rr = c + 16 * s;
        koff[s][0] = rr * 64 + (((g    ) ^ (rr & 7)) << 3);
        koff[s][1] = rr * 64 + (((g + 4) ^ (rr & 7)) << 3);
    }
    int voff2[4][2];
#pragma unroll
    for (int s = 0; s < 4; ++s) {
        const int rv = 16 * s + c;
        voff2[s][0] = rv * 64 + (((g    ) ^ (rv & 7)) << 3);
        voff2[s][1] = rv * 64 + (((g + 4) ^ (rv & 7)) << 3);
    }

    const float scale2 = 0.125f * 1.44269504f;   // 1/sqrt(64) * log2(e)

    // ---- pass 1: row sums of exp2(s*scale2), each group over its half ---
    float l = 0.f;

    auto sum_tile = [&](const short* Kb) {
        f32x4 a0 = {0.f,0.f,0.f,0.f}, a1 = {0.f,0.f,0.f,0.f};
        f32x4 a2 = {0.f,0.f,0.f,0.f}, a3 = {0.f,0.f,0.f,0.f};
        __builtin_amdgcn_s_setprio(1);
        a0 = __builtin_amdgcn_mfma_f32_16x16x32_bf16(*(const bf16x8*)(Kb + koff[0][0]), qf0, a0, 0, 0, 0);
        a0 = __builtin_amdgcn_mfma_f32_16x16x32_bf16(*(const bf16x8*)(Kb + koff[0][1]), qf1, a0, 0, 0, 0);
        a1 = __builtin_amdgcn_mfma_f32_16x16x32_bf16(*(const bf16x8*)(Kb + koff[1][0]), qf0, a1, 0, 0, 0);
        a1 = __builtin_amdgcn_mfma_f32_16x16x32_bf16(*(const bf16x8*)(Kb + koff[1][1]), qf1, a1, 0, 0, 0);
        a2 = __builtin_amdgcn_mfma_f32_16x16x32_bf16(*(const bf16x8*)(Kb + koff[2][0]), qf0, a2, 0, 0, 0);
        a2 = __builtin_amdgcn_mfma_f32_16x16x32_bf16(*(const bf16x8*)(Kb + koff[2][1]), qf1, a2, 0, 0, 0);
        a3 = __builtin_amdgcn_mfma_f32_16x16x32_bf16(*(const bf16x8*)(Kb + koff[3][0]), qf0, a3, 0, 0, 0);
        a3 = __builtin_amdgcn_mfma_f32_16x16x32_bf16(*(const bf16x8*)(Kb + koff[3][1]), qf1, a3, 0, 0, 0);
        __builtin_amdgcn_s_setprio(0);
        float ts = 0.f;
#pragma unroll
        for (int r = 0; r < 4; ++r) {
            ts += __builtin_amdgcn_exp2f(a0[r] * scale2);
            ts += __builtin_amdgcn_exp2f(a1[r] * scale2);
            ts += __builtin_amdgcn_exp2f(a2[r] * scale2);
            ts += __builtin_amdgcn_exp2f(a3[r] * scale2);
        }
        ts += __shfl_xor(ts, 16);
        ts += __shfl_xor(ts, 32);
        l += ts;
    };

    {
        uint4 kA = *(const uint4*)(kgb + (size_t)0  * 64 * HD + (size_t)t * 8);
        uint4 kB = *(const uint4*)(kgb + (size_t)16 * 64 * HD + (size_t)t * 8);
        *(uint4*)(&KsA[0][dss]) = kA;
        *(uint4*)(&KsB[0][dss]) = kB;
    }
    __syncthreads();
    int cur = 0;
    for (int ktl = 0; ktl < 16; ++ktl) {
        uint4 nA, nB;
        if (ktl < 15) {
            nA = *(const uint4*)(kgb + (size_t)(ktl + 1)  * 64 * HD + (size_t)t * 8);
            nB = *(const uint4*)(kgb + (size_t)(ktl + 17) * 64 * HD + (size_t)t * 8);
        }
        sum_tile(grp ? &KsB[cur][0] : &KsA[cur][0]);
        if (ktl < 15) {
            *(uint4*)(&KsA[cur ^ 1][dss]) = nA;
            *(uint4*)(&KsB[cur ^ 1][dss]) = nB;
        }
        __syncthreads();
        cur ^= 1;
    }

    lx[t] = l;
    __syncthreads();
    l = lx[t] + lx[t ^ 256];
    const float c0 = -__builtin_amdgcn_logf(l);   // p = exp2(s*scale2 + c0)
    __syncthreads();

    // ---- pass 2: weights + PV over this group's half --------------------
    f32x4 o0 = {0.f,0.f,0.f,0.f}, o1 = {0.f,0.f,0.f,0.f};
    f32x4 o2 = {0.f,0.f,0.f,0.f}, o3 = {0.f,0.f,0.f,0.f};
    float* __restrict__ wrow = wts + ((size_t)bh * SEQ + q) * SEQ;

    auto pv_tile = [&](const short* Kb, const short* Vb, int kv0) {
        f32x4 a0 = {0.f,0.f,0.f,0.f}, a1 = {0.f,0.f,0.f,0.f};
        f32x4 a2 = {0.f,0.f,0.f,0.f}, a3 = {0.f,0.f,0.f,0.f};
        __builtin_amdgcn_s_setprio(1);
        a0 = __builtin_amdgcn_mfma_f32_16x16x32_bf16(*(const bf16x8*)(Kb + koff[0][0]), qf0, a0, 0, 0, 0);
        a0 = __builtin_amdgcn_mfma_f32_16x16x32_bf16(*(const bf16x8*)(Kb + koff[0][1]), qf1, a0, 0, 0, 0);
        a1 = __builtin_amdgcn_mfma_f32_16x16x32_bf16(*(const bf16x8*)(Kb + koff[1][0]), qf0, a1, 0, 0, 0);
        a1 = __builtin_amdgcn_mfma_f32_16x16x32_bf16(*(const bf16x8*)(Kb + koff[1][1]), qf1, a1, 0, 0, 0);
        a2 = __builtin_amdgcn_mfma_f32_16x16x32_bf16(*(const bf16x8*)(Kb + koff[2][0]), qf0, a2, 0, 0, 0);
        a2 = __builtin_amdgcn_mfma_f32_16x16x32_bf16(*(const bf16x8*)(Kb + koff[2][1]), qf1, a2, 0, 0, 0);
        a3 = __builtin_amdgcn_mfma_f32_16x16x32_bf16(*(const bf16x8*)(Kb + koff[3][0]), qf0, a3, 0, 0, 0);
        a3 = __builtin_amdgcn_mfma_f32_16x16x32_bf16(*(const bf16x8*)(Kb + koff[3][1]), qf1, a3, 0, 0, 0);
        __builtin_amdgcn_s_setprio(0);

        float pn[4][4];
#pragma unroll
        for (int r = 0; r < 4; ++r) {
            pn[0][r] = __builtin_amdgcn_exp2f(fmaf(a0[r], scale2, c0));
            pn[1][r] = __builtin_amdgcn_exp2f(fmaf(a1[r], scale2, c0));
            pn[2][r] = __builtin_amdgcn_exp2f(fmaf(a2[r], scale2, c0));
            pn[3][r] = __builtin_amdgcn_exp2f(fmaf(a3[r], scale2, c0));
        }
        union { bf16x8 v; unsigned u[4]; } pf0, pf1;
        pf0.u[0] = (__float_as_uint(pn[0][0]) >> 16) | (__float_as_uint(pn[0][1]) & 0xffff0000u);
        pf0.u[1] = (__float_as_uint(pn[0][2]) >> 16) | (__float_as_uint(pn[0][3]) & 0xffff0000u);
        pf0.u[2] = (__float_as_uint(pn[1][0]) >> 16) | (__float_as_uint(pn[1][1]) & 0xffff0000u);
        pf0.u[3] = (__float_as_uint(pn[1][2]) >> 16) | (__float_as_uint(pn[1][3]) & 0xffff0000u);
        pf1.u[0] = (__float_as_uint(pn[2][0]) >> 16) | (__float_as_uint(pn[2][1]) & 0xffff0000u);
        pf1.u[1] = (__float_as_uint(pn[2][2]) >> 16) | (__float_as_uint(pn[2][3]) & 0xffff0000u);
        pf1.u[2] = (__float_as_uint(pn[3][0]) >> 16) | (__float_as_uint(pn[3][1]) & 0xffff0000u);
        pf1.u[3] = (__float_as_uint(pn[3][2]) >> 16) | (__float_as_uint(pn[3][3]) & 0xffff0000u);

        __builtin_amdgcn_s_setprio(1);
#pragma unroll
        for (int sub = 0; sub < 4; ++sub) {
            const bf16x8 vf0 = *(const bf16x8*)(Vb + voff2[sub][0]);
            const bf16x8 vf1 = *(const bf16x8*)(Vb + voff2[sub][1]);
            f32x4& o = (sub == 0) ? o0 : (sub == 1) ? o1 : (sub == 2) ? o2 : o3;
            o = __builtin_amdgcn_mfma_f32_16x16x32_bf16(pf0.v, vf0, o, 0, 0, 0);
            o = __builtin_amdgcn_mfma_f32_16x16x32_bf16(pf1.v, vf1, o, 0, 0, 0);
        }
        __builtin_amdgcn_s_setprio(0);
#pragma unroll
        for (int s = 0; s < 4; ++s) {
            float4 st;
            st.x = pn[s][0]; st.y = pn[s][1]; st.z = pn[s][2]; st.w = pn[s][3];
            *(float4*)(wrow + kv0 + 16 * s + 4 * g) = st;
        }
    };

    {
        uint4 kA = *(const uint4*)(kgb + (size_t)0  * 64 * HD + (size_t)t * 8);
        uint4 kB = *(const uint4*)(kgb + (size_t)16 * 64 * HD + (size_t)t * 8);
        uint4 vA = *(const uint4*)(vgb + (size_t)rs * SEQ + 0    + bls * 8);
        uint4 vB = *(const uint4*)(vgb + (size_t)rs * SEQ + 1024 + bls * 8);
        *(uint4*)(&KsA[0][dss]) = kA;  *(uint4*)(&KsB[0][dss]) = kB;
        *(uint4*)(&VsA[0][dss]) = vA;  *(uint4*)(&VsB[0][dss]) = vB;
    }
    __syncthreads();
    cur = 0;
    for (int ktl = 0; ktl < 16; ++ktl) {
        uint4 nKA, nKB, nVA, nVB;
        if (ktl < 15) {
            nKA = *(const uint4*)(kgb + (size_t)(ktl + 1)  * 64 * HD + (size_t)t * 8);
            nKB = *(const uint4*)(kgb + (size_t)(ktl + 17) * 64 * HD + (size_t)t * 8);
            nVA = *(const uint4*)(vgb + (size_t)rs * SEQ + (ktl + 1)  * 64 + bls * 8);
            nVB = *(const uint4*)(vgb + (size_t)rs * SEQ + (ktl + 17) * 64 + bls * 8);
        }
        if (grp == 0) pv_tile(&KsA[cur][0], &VsA[cur][0], ktl * 64);
        else          pv_tile(&KsB[cur][0], &VsB[cur][0], 1024 + ktl * 64);
        if (ktl < 15) {
            *(uint4*)(&KsA[cur ^ 1][dss]) = nKA;  *(uint4*)(&KsB[cur ^ 1][dss]) = nKB;
            *(uint4*)(&VsA[cur ^ 1][dss]) = nVA;  *(uint4*)(&VsB[cur ^ 1][dss]) = nVB;
        }
        __syncthreads();
        cur ^= 1;
    }

    // ---- merge partial O across groups, write bf16 hi/lo attn -----------
    float* sc = (float*)&KsA[0][0];   // 16 KB scratch
    if (w >= 4) {
        const int base = ((w - 4) * 64 + lane) * 16;
#pragma unroll
        for (int r = 0; r < 4; ++r) {
            sc[base + 0  + r] = o0[r];
            sc[base + 4  + r] = o1[r];
            sc[base + 8  + r] = o2[r];
            sc[base + 12 + r] = o3[r];
        }
    }
    __syncthreads();
    if (w < 4) {
        const int base = (w * 64 + lane) * 16;
        const size_t abase = ((size_t)bh * SEQ + q0 + 16 * w) * HD;
#pragma unroll
        for (int r = 0; r < 4; ++r) {
            const float v0 = o0[r] + sc[base + 0  + r];
            const float v1 = o1[r] + sc[base + 4  + r];
            const float v2 = o2[r] + sc[base + 8  + r];
            const float v3 = o3[r] + sc[base + 12 + r];
            const size_t ro = abase + (size_t)(4 * g + r) * HD + c;
            unsigned short h16;
            h16 = f2bf(v0); attn_h[ro +  0] = h16; attn_l[ro +  0] = f2bf(v0 - bf2f(h16));
            h16 = f2bf(v1); attn_h[ro + 16] = h16; attn_l[ro + 16] = f2bf(v1 - bf2f(h16));
            h16 = f2bf(v2); attn_h[ro + 32] = h16; attn_l[ro + 32] = f2bf(v2 - bf2f(h16));
            h16 = f2bf(v3); attn_h[ro + 48] = h16; attn_l[ro + 48] = f2bf(v3 - bf2f(h16));
        }
    }
}

// ---------------------------------------------------------------------------
// K3: out = concat(attn) @ Wo + bo on MFMA, ALL OPERANDS LDS-STAGED
// (R14-verified).  Block 64m x 64n, 4 waves; K-loop over 8 heads.
// ---------------------------------------------------------------------------
__global__ __launch_bounds__(256) void mha_oproj_mfma(
    const unsigned short* __restrict__ ath, const unsigned short* __restrict__ atl,
    const unsigned short* __restrict__ wto,
    const float* __restrict__ bo, float* __restrict__ out)
{
    __shared__ short Ah[4096], Al[4096], Bh[4096], Bl[4096];   // [64 row][64 k]

    const int m0 = blockIdx.x * 64;
    const int n0 = blockIdx.y * 64;
    const int t = threadIdx.x;
    const int w = t >> 6;
    const int lane = t & 63;
    const int g = lane >> 4;
    const int c = lane & 15;

    const int rs = t >> 3, bls = t & 7;
    const int ds0 = rs * 64 + ((bls ^ (rs & 7)) << 3);
    const int rs1 = rs + 32;
    const int ds1 = rs1 * 64 + ((bls ^ (rs1 & 7)) << 3);

    const int b_ = m0 >> 11;
    const size_t abase0 = ((size_t)(b_ * NHEADS) * SEQ + (m0 & 2047)) * HD;
    const size_t aoffr0 = (size_t)rs  * HD + bls * 8;
    const size_t aoffr1 = (size_t)rs1 * HD + bls * 8;
    const short* wh_g = (const short*)wto + (size_t)(n0 + rs)  * EMBED + bls * 8;
    const short* wh_g1 = (const short*)wto + (size_t)(n0 + rs1) * EMBED + bls * 8;
    const short* wl_g  = wh_g  + (size_t)EMBED * EMBED;
    const short* wl_g1 = wh_g1 + (size_t)EMBED * EMBED;

    int aoff[2];
    {
        const int rr = 16 * w + c;
        aoff[0] = rr * 64 + (((g    ) ^ (rr & 7)) << 3);
        aoff[1] = rr * 64 + (((g + 4) ^ (rr & 7)) << 3);
    }
    int boff[4][2];
#pragma unroll
    for (int s = 0; s < 4; ++s) {
        const int rr = 16 * s + c;
        boff[s][0] = rr * 64 + (((g    ) ^ (rr & 7)) << 3);
        boff[s][1] = rr * 64 + (((g + 4) ^ (rr & 7)) << 3);
    }

    f32x4 acc[4];
#pragma unroll
    for (int s = 0; s < 4; ++s) acc[s] = (f32x4){0.f, 0.f, 0.f, 0.f};

    {
        const short* ag = (const short*)ath + abase0;
        const short* lg = (const short*)atl + abase0;
        *(uint4*)(&Ah[ds0]) = *(const uint4*)(ag + aoffr0);
        *(uint4*)(&Ah[ds1]) = *(const uint4*)(ag + aoffr1);
        *(uint4*)(&Al[ds0]) = *(const uint4*)(lg + aoffr0);
        *(uint4*)(&Al[ds1]) = *(const uint4*)(lg + aoffr1);
        *(uint4*)(&Bh[ds0]) = *(const uint4*)(wh_g);
        *(uint4*)(&Bh[ds1]) = *(const uint4*)(wh_g1);
        *(uint4*)(&Bl[ds0]) = *(const uint4*)(wl_g);
        *(uint4*)(&Bl[ds1]) = *(const uint4*)(wl_g1);
    }
    __syncthreads();

    for (int h = 0; h < 8; ++h) {
        uint4 nA0, nA1, nL0, nL1, nB0, nB1, nC0, nC1;
        if (h < 7) {
            const short* ag = (const short*)ath + abase0 + (size_t)(h + 1) * SEQ * HD;
            const short* lg = (const short*)atl + abase0 + (size_t)(h + 1) * SEQ * HD;
            nA0 = *(const uint4*)(ag + aoffr0);
            nA1 = *(const uint4*)(ag + aoffr1);
            nL0 = *(const uint4*)(lg + aoffr0);
            nL1 = *(const uint4*)(lg + aoffr1);
            nB0 = *(const uint4*)(wh_g  + (h + 1) * 64);
            nB1 = *(const uint4*)(wh_g1 + (h + 1) * 64);
            nC0 = *(const uint4*)(wl_g  + (h + 1) * 64);
            nC1 = *(const uint4*)(wl_g1 + (h + 1) * 64);
        }

        const bf16x8 ah0 = *(const bf16x8*)(Ah + aoff[0]);
        const bf16x8 ah1 = *(const bf16x8*)(Ah + aoff[1]);
        const bf16x8 al0 = *(const bf16x8*)(Al + aoff[0]);
        const bf16x8 al1 = *(const bf16x8*)(Al + aoff[1]);
        __builtin_amdgcn_s_setprio(1);
#pragma unroll
        for (int s = 0; s < 4; ++s) {
            const bf16x8 bh0 = *(const bf16x8*)(Bh + boff[s][0]);
            const bf16x8 bh1 = *(const bf16x8*)(Bh + boff[s][1]);
            const bf16x8 bl0 = *(const bf16x8*)(Bl + boff[s][0]);
            const bf16x8 bl1 = *(const bf16x8*)(Bl + boff[s][1]);
            acc[s] = __builtin_amdgcn_mfma_f32_16x16x32_bf16(ah0, bh0, acc[s], 0, 0, 0);
            acc[s] = __builtin_amdgcn_mfma_f32_16x16x32_bf16(ah1, bh1, acc[s], 0, 0, 0);
            acc[s] = __builtin_amdgcn_mfma_f32_16x16x32_bf16(al0, bh0, acc[s], 0, 0, 0);
            acc[s] = __builtin_amdgcn_mfma_f32_16x16x32_bf16(al1, bh1, acc[s], 0, 0, 0);
            acc[s] = __builtin_amdgcn_mfma_f32_16x16x32_bf16(ah0, bl0, acc[s], 0, 0, 0);
            acc[s] = __builtin_amdgcn_mfma_f32_16x16x32_bf16(ah1, bl1, acc[s], 0, 0, 0);
        }
        __builtin_amdgcn_s_setprio(0);

        __syncthreads();
        if (h < 7) {
            *(uint4*)(&Ah[ds0]) = nA0;  *(uint4*)(&Ah[ds1]) = nA1;
            *(uint4*)(&Al[ds0]) = nL0;  *(uint4*)(&Al[ds1]) = nL1;
            *(uint4*)(&Bh[ds0]) = nB0;  *(uint4*)(&Bh[ds1]) = nB1;
            *(uint4*)(&Bl[ds0]) = nC0;  *(uint4*)(&Bl[ds1]) = nC1;
        }
        __syncthreads();
    }

#pragma unroll
    for (int s = 0; s < 4; ++s) {
        const int n = n0 + 16 * s + c;
        const float bb = bo[n];
#pragma unroll
        for (int r = 0; r < 4; ++r) {
            const int m = m0 + 16 * w + 4 * g + r;
            out[(size_t)m * EMBED + n] = acc[s][r] + bb;
        }
    }
}

// ---------------------------------------------------------------------------
extern "C" void kernel_launch(void* const* d_in, const int* in_sizes, int n_in,
                              void* d_out, int out_size, void* d_ws, size_t ws_size,
                              hipStream_t stream)
{
    const float* x  = (const float*)d_in[0];
    const float* Wq = (const float*)d_in[1];
    const float* bq = (const float*)d_in[2];
    const float* Wk = (const float*)d_in[3];
    const float* bk = (const float*)d_in[4];
    const float* Wv = (const float*)d_in[5];
    const float* bv = (const float*)d_in[6];
    const float* Wo = (const float*)d_in[7];
    const float* bo = (const float*)d_in[8];

    float* out = (float*)d_out;                      // [2,2048,512]
    float* wts = out + (size_t)2 * SEQ * EMBED;      // [2,8,2048,2048]

    unsigned short* qbw = (unsigned short*)d_ws;             // bf16 [16][2048][64]
    unsigned short* kbw = qbw + (size_t)NBH * SEQ * HD;      // bf16 [16][2048][64]
    unsigned short* vtw = kbw + (size_t)NBH * SEQ * HD;      // bf16 [16][64][2048] (kv-permuted)
    unsigned short* ath = vtw + (size_t)NBH * SEQ * HD;      // bf16 [16][2048][64]
    unsigned short* atl = ath + (size_t)NBH * SEQ * HD;      // bf16 [16][2048][64]
    unsigned short* xh  = atl + (size_t)NBH * SEQ * HD;      // bf16 [4096][512]
    unsigned short* xl  = xh + (size_t)MROWS * EMBED;        // bf16 [4096][512]
    unsigned short* wtw = xl + (size_t)MROWS * EMBED;        // bf16 [3][512][512]
    unsigned short* wto = wtw + (size_t)3 * EMBED * EMBED;   // bf16 [2][512][512]

    cvt_x<<<dim3(MROWS * EMBED / 4 / 256), 256, 0, stream>>>(x, xh, xl);
    cvt_w<<<dim3(8, 8, 5), 256, 0, stream>>>(Wq, Wk, Wv, Wo, wtw, wto);
    mha_qkv_mfma<<<dim3(64, 24), 256, 0, stream>>>(xh, xl, wtw, bq, bk, bv,
                                                   qbw, kbw, vtw);
    mha_fused  <<<dim3(32, NBH), 512, 0, stream>>>((const short*)qbw, (const short*)kbw,
                                                   (const short*)vtw, wts, ath, atl);
    mha_oproj_mfma<<<dim3(64, 8), 256, 0, stream>>>(ath, atl, wto, bo, out);
}